// Round 5
// baseline (312.851 us; speedup 1.0000x reference)
//
#include <hip/hip_runtime.h>
#include <stdint.h>

#define B_ 4
#define S_ 1024
#define D_ 512
#define H_ 8
#define DH_ 64
#define INNER_ 1536
#define M_ (B_*S_)   // 4096

typedef unsigned short u16;
typedef __attribute__((ext_vector_type(8))) short sh8;      // 8 bf16
typedef __attribute__((ext_vector_type(8))) _Float16 h8;    // 8 f16
typedef __attribute__((ext_vector_type(4))) _Float16 h4;    // 4 f16
typedef __attribute__((ext_vector_type(2))) _Float16 h2f;   // 2 f16
typedef __attribute__((ext_vector_type(2))) unsigned short us2;
typedef __attribute__((ext_vector_type(4))) float f32x4;

typedef __attribute__((address_space(1))) const void cgv;
typedef __attribute__((address_space(3))) void lv;
__device__ __forceinline__ void gl_lds16(const void* g, void* l) {
  __builtin_amdgcn_global_load_lds((cgv*)g, (lv*)l, 16, 0, 0);
}

__device__ __forceinline__ float bf2f(u16 u) {
  union { unsigned int i; float f; } v; v.i = ((unsigned int)u) << 16; return v.f;
}
__device__ __forceinline__ u16 f2bf(float f) {
  union { float f; unsigned int i; } v; v.f = f;
  unsigned int u = v.i;
  return (u16)((u + 0x7FFFu + ((u >> 16) & 1u)) >> 16);
}
__device__ __forceinline__ u16 f2h(float f) {
  _Float16 h = (_Float16)f;
  return *(u16*)&h;
}
__device__ __forceinline__ float h_lo(uint32_t v) {
  h2f h = __builtin_bit_cast(h2f, v); return (float)h[0];
}
__device__ __forceinline__ float h_hi(uint32_t v) {
  h2f h = __builtin_bit_cast(h2f, v); return (float)h[1];
}

// ---------------- prep: x -> bf16, tmpF = x + bo[col] ----------------
__global__ __launch_bounds__(256) void prep_kernel(const float* __restrict__ x,
                                                   const float* __restrict__ bo,
                                                   u16* __restrict__ xb,
                                                   float* __restrict__ tmpF) {
  int i = (blockIdx.x * 256 + threadIdx.x) * 4;
  float4 v = *(const float4*)(x + i);
  uint2 o;
  o.x = (unsigned int)f2bf(v.x) | ((unsigned int)f2bf(v.y) << 16);
  o.y = (unsigned int)f2bf(v.z) | ((unsigned int)f2bf(v.w) << 16);
  *(uint2*)(xb + i) = o;
  int col = i & 511;
  float4 b = *(const float4*)(bo + col);
  float4 t; t.x = v.x + b.x; t.y = v.y + b.y; t.z = v.z + b.z; t.w = v.w + b.w;
  *(float4*)(tmpF + i) = t;
}

// ---------------- all weight transposes in one launch ----------------
__global__ __launch_bounds__(256) void transpose_all(
    const float* __restrict__ Wq, const float* __restrict__ Wkv,
    const float* __restrict__ Wo, const float* __restrict__ l1,
    const float* __restrict__ l2, const float* __restrict__ l3,
    u16* __restrict__ Wt1, u16* __restrict__ Wot,
    u16* __restrict__ W12t, u16* __restrict__ l3t)
{
  int i = blockIdx.x;
  const float* in; u16* outp; int K, N, bx, by;
  if (i < 64)       { in = Wq;  outp = Wt1;              K = 512;  N = 512;           bx = i & 7;  by = i >> 3; }
  else if (i < 192) { in = Wkv; outp = Wt1 + 512 * 512;  K = 512;  N = 1024; i -= 64; bx = i & 15; by = i >> 4; }
  else if (i < 256) { in = Wo;  outp = Wot;              K = 512;  N = 512;  i -= 192; bx = i & 7;  by = i >> 3; }
  else if (i < 448) { in = l1;  outp = W12t;             K = 512;  N = 1536; i -= 256; bx = i % 24; by = i / 24; }
  else if (i < 640) { in = l2;  outp = W12t + 1536 * 512; K = 512; N = 1536; i -= 448; bx = i % 24; by = i / 24; }
  else              { in = l3;  outp = l3t;              K = 1536; N = 512;  i -= 640; bx = i & 7;  by = i >> 3; }

  __shared__ u16 tile[64][65];
  int tx = threadIdx.x & 63, ty = threadIdx.x >> 6;
  int n0 = bx * 64, k0 = by * 64;
  #pragma unroll
  for (int t = 0; t < 16; t++) {
    int k = ty + t * 4;
    tile[k][tx] = f2bf(in[(size_t)(k0 + k) * N + n0 + tx]);
  }
  __syncthreads();
  #pragma unroll
  for (int t = 0; t < 16; t++) {
    int n = ty + t * 4;
    outp[(size_t)(n0 + n) * K + k0 + tx] = tile[tx][n];
  }
}

// ---------------- 128x128 GEMM, glds staging ----------------
// EPI 1: qkv scatter (+biases), q/k/v stored f16 ; EPI 3: plain -> outU bf16
template<int EPI>
__global__ __launch_bounds__(256) void gemm_bt(
    const u16* __restrict__ A, const u16* __restrict__ Bt,
    int M, int N, int K,
    const float* __restrict__ bias0, const float* __restrict__ bias1,
    u16* __restrict__ outU,
    u16* __restrict__ qo, u16* __restrict__ ko_, u16* __restrict__ vto)
{
  __shared__ u16 As[128 * 32];
  __shared__ u16 Bs[128 * 32];
  int tid = threadIdx.x;
  int gx = blockIdx.x, gy = blockIdx.y;
  int l = tid & 63, w = tid >> 6;
  int l15 = l & 15, quad = l >> 4;
  int wm = (w >> 1) * 64, wn = (w & 1) * 64;
  f32x4 acc[4][4] = {};

  const u16* Ag = A  + (size_t)(gy * 128 + (tid >> 2)) * K + (tid & 3) * 8;
  const u16* Bg = Bt + (size_t)(gx * 128 + (tid >> 2)) * K + (tid & 3) * 8;

  for (int ko = 0; ko < K; ko += 32) {
    __syncthreads();
    gl_lds16(Ag + ko,                  &As[tid * 8]);
    gl_lds16(Ag + (size_t)64 * K + ko, &As[2048 + tid * 8]);
    gl_lds16(Bg + ko,                  &Bs[tid * 8]);
    gl_lds16(Bg + (size_t)64 * K + ko, &Bs[2048 + tid * 8]);
    __syncthreads();
    sh8 af[4], bfr[4];
    #pragma unroll
    for (int mi = 0; mi < 4; mi++)
      af[mi] = *(const sh8*)&As[(wm + mi * 16 + l15) * 32 + quad * 8];
    #pragma unroll
    for (int ni = 0; ni < 4; ni++)
      bfr[ni] = *(const sh8*)&Bs[(wn + ni * 16 + l15) * 32 + quad * 8];
    #pragma unroll
    for (int mi = 0; mi < 4; mi++)
      #pragma unroll
      for (int ni = 0; ni < 4; ni++)
        acc[mi][ni] = __builtin_amdgcn_mfma_f32_16x16x32_bf16(af[mi], bfr[ni], acc[mi][ni], 0, 0, 0);
  }

  #pragma unroll
  for (int mi = 0; mi < 4; mi++) {
    #pragma unroll
    for (int ni = 0; ni < 4; ni++) {
      #pragma unroll
      for (int r = 0; r < 4; r++) {
        int grow = gy * 128 + wm + mi * 16 + quad * 4 + r;
        int gcol = gx * 128 + wn + ni * 16 + l15;
        float v = acc[mi][ni][r];
        if (EPI == 1) {
          int b = grow >> 10, s = grow & 1023;
          if (gcol < 512) {
            int h = gcol >> 6, dh = gcol & 63;
            qo[(((size_t)b * H_ + h) * S_ + s) * DH_ + dh] = f2h(v + bias0[gcol]);
          } else {
            int n2 = gcol - 512;
            int two = n2 >> 9, h = (n2 >> 6) & 7, dh = n2 & 63;
            float vv = v + bias1[n2];
            if (two == 0) ko_[(((size_t)b * H_ + h) * S_ + s) * DH_ + dh] = f2h(vv);
            else          vto[(((size_t)b * H_ + h) * DH_ + dh) * S_ + s] = f2h(vv);
          }
        } else {
          outU[(size_t)grow * N + gcol] = f2bf(v);
        }
      }
    }
  }
}

// ---------------- 128x128 split-K GEMM, atomic f32 epilogue ----------------
__global__ __launch_bounds__(256) void gemm_sk(
    const u16* __restrict__ A, const u16* __restrict__ Bt,
    int N, int K, int KH, float* __restrict__ outF)
{
  __shared__ u16 As[128 * 32];
  __shared__ u16 Bs[128 * 32];
  int tid = threadIdx.x;
  int gx = blockIdx.x, gy = blockIdx.y, gz = blockIdx.z;
  int l = tid & 63, w = tid >> 6;
  int l15 = l & 15, quad = l >> 4;
  int wm = (w >> 1) * 64, wn = (w & 1) * 64;
  f32x4 acc[4][4] = {};

  const u16* Ag = A  + (size_t)(gy * 128 + (tid >> 2)) * K + gz * KH + (tid & 3) * 8;
  const u16* Bg = Bt + (size_t)(gx * 128 + (tid >> 2)) * K + gz * KH + (tid & 3) * 8;

  for (int ko = 0; ko < KH; ko += 32) {
    __syncthreads();
    gl_lds16(Ag + ko,                  &As[tid * 8]);
    gl_lds16(Ag + (size_t)64 * K + ko, &As[2048 + tid * 8]);
    gl_lds16(Bg + ko,                  &Bs[tid * 8]);
    gl_lds16(Bg + (size_t)64 * K + ko, &Bs[2048 + tid * 8]);
    __syncthreads();
    sh8 af[4], bfr[4];
    #pragma unroll
    for (int mi = 0; mi < 4; mi++)
      af[mi] = *(const sh8*)&As[(wm + mi * 16 + l15) * 32 + quad * 8];
    #pragma unroll
    for (int ni = 0; ni < 4; ni++)
      bfr[ni] = *(const sh8*)&Bs[(wn + ni * 16 + l15) * 32 + quad * 8];
    #pragma unroll
    for (int mi = 0; mi < 4; mi++)
      #pragma unroll
      for (int ni = 0; ni < 4; ni++)
        acc[mi][ni] = __builtin_amdgcn_mfma_f32_16x16x32_bf16(af[mi], bfr[ni], acc[mi][ni], 0, 0, 0);
  }

  #pragma unroll
  for (int mi = 0; mi < 4; mi++) {
    #pragma unroll
    for (int ni = 0; ni < 4; ni++) {
      #pragma unroll
      for (int r = 0; r < 4; r++) {
        int grow = gy * 128 + wm + mi * 16 + quad * 4 + r;
        int gcol = gx * 128 + wn + ni * 16 + l15;
        atomicAdd(&outF[(size_t)grow * N + gcol], acc[mi][ni][r]);
      }
    }
  }
}

// ---------------- sparse attention v3: packed-key bisect, 32KB swizzled LDS ----------------
__global__ __launch_bounds__(256, 5) void attn_kernel(
    const u16* __restrict__ q, const u16* __restrict__ kk,
    const u16* __restrict__ vt, u16* __restrict__ attn)
{
  __shared__ u16 scb[16 * 1024];   // exactly 32 KB; rows of 1024 halves, 4-half chunks XOR-swizzled by row

  int tid = threadIdx.x;
  int l = tid & 63, w = tid >> 6;
  int l15 = l & 15, quad = l >> 4;
  int blk = blockIdx.x;
  int bh = blk >> 6;             // b*8+h
  int r0 = (blk & 63) << 4;      // query tile start

  const u16* qb = q  + ((size_t)bh * S_ + r0) * DH_;
  const u16* kb = kk + (size_t)bh * S_ * DH_;
  const u16* vb = vt + (size_t)bh * DH_ * S_;

  h8 aq0 = *(const h8*)(qb + l15 * DH_ + quad * 8);
  h8 aq1 = *(const h8*)(qb + l15 * DH_ + 32 + quad * 8);

  // ---- phase A: scores = (K Q^T)/8 -> LDS f16, swizzled chunks
  #pragma unroll
  for (int i = 0; i < 16; i++) {
    int t0 = ((i << 2) | w) << 4;
    const u16* kr = kb + (size_t)(t0 + l15) * DH_;
    h8 bk0 = *(const h8*)(kr + quad * 8);
    h8 bk1 = *(const h8*)(kr + 32 + quad * 8);
    f32x4 s4 = {};
    s4 = __builtin_amdgcn_mfma_f32_16x16x32_f16(bk0, aq0, s4, 0, 0, 0);
    s4 = __builtin_amdgcn_mfma_f32_16x16x32_f16(bk1, aq1, s4, 0, 0, 0);
    h4 hv;
    #pragma unroll
    for (int r = 0; r < 4; r++) hv[r] = (_Float16)(s4[r] * 0.125f);
    int cc = ((t0 >> 2) + quad) ^ l15;   // chunk index, swizzled
    *(h4*)(scb + l15 * 1024 + (cc << 2)) = hv;
  }
  __syncthreads();   // B1

  // ---- phase B: registers only. 64 scores per thread as 32 packed words.
  int row = tid >> 4, l16 = tid & 15;
  u16* rowp = scb + row * 1024;
  uint32_t kv[32];
  float Z1 = 0.f;
  #pragma unroll
  for (int u = 0; u < 16; u++) {
    int cc = (l16 + (u << 4)) ^ row;
    uint2 rr = *(const uint2*)(rowp + (cc << 2));
    uint32_t v0 = rr.x, v1 = rr.y;
    Z1 += __expf(h_lo(v0)) + __expf(h_hi(v0)) + __expf(h_lo(v1)) + __expf(h_hi(v1));
    uint32_t m0 = v0 & 0x80008000u;
    uint32_t m1 = v1 & 0x80008000u;
    kv[2 * u]     = v0 ^ (0x80008000u | ((m0 >> 15) * 0x7FFFu));  // monotone 16-bit keys
    kv[2 * u + 1] = v1 ^ (0x80008000u | ((m1 >> 15) * 0x7FFFu));
  }
  #pragma unroll
  for (int d = 1; d < 16; d <<= 1) Z1 += __shfl_xor(Z1, d);
  float invZ = 1.0f / Z1;

  // bisect top 12 bits of the key threshold: largest T (low 4 bits 0) with count(key>=T) >= 512
  us2 onep; onep[0] = 1; onep[1] = 1;
  uint32_t lo = 0;
  #pragma unroll
  for (int bit = 15; bit >= 4; bit--) {
    uint32_t cand = lo | (1u << bit);
    uint32_t tm1 = cand - 1u;
    us2 tp; tp[0] = (unsigned short)tm1; tp[1] = (unsigned short)tm1;
    uint32_t acc = 0;
    #pragma unroll
    for (int t = 0; t < 32; t++) {
      us2 a = __builtin_bit_cast(us2, kv[t]);
      us2 d = __builtin_elementwise_sub_sat(a, tp);   // v_pk_sub_u16 clamp
      d = __builtin_elementwise_min(d, onep);         // v_pk_min_u16
      acc += __builtin_bit_cast(uint32_t, d);
    }
    uint32_t cnt = (acc & 0xFFFFu) + (acc >> 16);
    #pragma unroll
    for (int d2 = 1; d2 < 16; d2 <<= 1) cnt += __shfl_xor(cnt, d2);
    if (cnt >= 512u) lo = cand;
  }

  // coefficients c = kept ? exp(w) : 1, packed f16 back into kv
  float Z2 = 0.f;
  #pragma unroll
  for (int t = 0; t < 32; t++) {
    uint32_t km = kv[t];
    uint32_t nb = (~km) & 0x80008000u;
    uint32_t raw = km ^ (0x80008000u | ((nb >> 15) * 0x7FFFu));
    float w0 = __expf(h_lo(raw)) * invZ;
    float w1 = __expf(h_hi(raw)) * invZ;
    float c0 = ((km & 0xFFFFu) >= lo) ? __expf(w0) : 1.0f;
    float c1 = ((km >> 16)     >= lo) ? __expf(w1) : 1.0f;
    Z2 += c0 + c1;
    h2f cp; cp[0] = (_Float16)c0; cp[1] = (_Float16)c1;
    kv[t] = __builtin_bit_cast(uint32_t, cp);
  }
  #pragma unroll
  for (int d = 1; d < 16; d <<= 1) Z2 += __shfl_xor(Z2, d);
  _Float16 zh = (_Float16)(1.0f / Z2);
  h2f zp; zp[0] = zh; zp[1] = zh;

  // scale by 1/Z2 (v_pk_mul_f16) and store back to the same swizzled slots
  #pragma unroll
  for (int u = 0; u < 16; u++) {
    h2f a = __builtin_bit_cast(h2f, kv[2 * u]) * zp;
    h2f b = __builtin_bit_cast(h2f, kv[2 * u + 1]) * zp;
    uint2 ov;
    ov.x = __builtin_bit_cast(uint32_t, a);
    ov.y = __builtin_bit_cast(uint32_t, b);
    int cc = (l16 + (u << 4)) ^ row;
    *(uint2*)(rowp + (cc << 2)) = ov;
  }
  __syncthreads();   // B2

  // ---- phase E: o = c' @ V via f16 MFMA (coefficients already carry 1/Z2)
  int n0 = w << 4;
  const u16* crow = scb + l15 * 1024;
  f32x4 oacc = {};
  #pragma unroll
  for (int kt = 0; kt < 32; kt++) {
    int c0 = ((kt << 3) + (quad << 1)) ^ l15;
    int c1 = ((kt << 3) + (quad << 1) + 1) ^ l15;
    uint2 u0 = *(const uint2*)(crow + (c0 << 2));
    uint2 u1 = *(const uint2*)(crow + (c1 << 2));
    h8 ca;
    ((uint2*)&ca)[0] = u0;
    ((uint2*)&ca)[1] = u1;
    h8 vv = *(const h8*)(vb + (size_t)(n0 + l15) * S_ + kt * 32 + quad * 8);
    oacc = __builtin_amdgcn_mfma_f32_16x16x32_f16(ca, vv, oacc, 0, 0, 0);
  }
  int b = bh >> 3, hh = bh & 7;
  #pragma unroll
  for (int r = 0; r < 4; r++) {
    int rr = quad * 4 + r;
    attn[((size_t)b * S_ + r0 + rr) * D_ + hh * DH_ + n0 + l15] = f2bf(oacc[r]);
  }
}

// ---------------- RMS norm: bf16 hhat out + in-place fp32 h_hat (FFN-down acc init) ----------------
__global__ __launch_bounds__(128) void rms_kernel(float* __restrict__ io,
                                                  const float* __restrict__ w,
                                                  u16* __restrict__ out) {
  int row = blockIdx.x;
  int tid = threadIdx.x;
  float* r = io + (size_t)row * D_;
  float v0 = r[tid], v1 = r[tid + 128], v2 = r[tid + 256], v3 = r[tid + 384];
  float s = v0 * v0 + v1 * v1 + v2 * v2 + v3 * v3;
  #pragma unroll
  for (int d = 1; d < 64; d <<= 1) s += __shfl_xor(s, d);
  __shared__ float red[2];
  if ((tid & 63) == 0) red[tid >> 6] = s;
  __syncthreads();
  s = red[0] + red[1];
  float rs = rsqrtf(s * (1.0f / 512.0f) + 1e-6f);
  #pragma unroll
  for (int i = 0; i < 4; i++) {
    int d = tid + i * 128;
    float hv = (i == 0 ? v0 : i == 1 ? v1 : i == 2 ? v2 : v3) * rs * w[d];
    out[(size_t)row * D_ + d] = f2bf(hv);
    r[d] = hv;
  }
}

// ---------------- silu(a)*b (bf16 in/out) ----------------
__global__ __launch_bounds__(256) void silu_mul_kernel(const u16* __restrict__ ab,
                                                       u16* __restrict__ g) {
  size_t i = ((size_t)blockIdx.x * 256 + threadIdx.x) * 8;
  size_t m = i / INNER_, j = i % INNER_;
  const u16* pa = ab + m * (2 * INNER_) + j;
  uint4 av = *(const uint4*)pa;
  uint4 bv = *(const uint4*)(pa + INNER_);
  unsigned int aa[4] = {av.x, av.y, av.z, av.w};
  unsigned int bb[4] = {bv.x, bv.y, bv.z, bv.w};
  unsigned int rr[4];
  #pragma unroll
  for (int t = 0; t < 4; t++) {
    float a0 = bf2f((u16)(aa[t] & 0xFFFF)), a1 = bf2f((u16)(aa[t] >> 16));
    float b0 = bf2f((u16)(bb[t] & 0xFFFF)), b1 = bf2f((u16)(bb[t] >> 16));
    float c0 = a0 / (1.f + __expf(-a0)) * b0;
    float c1 = a1 / (1.f + __expf(-a1)) * b1;
    rr[t] = (unsigned int)f2bf(c0) | ((unsigned int)f2bf(c1) << 16);
  }
  uint4 o; o.x = rr[0]; o.y = rr[1]; o.z = rr[2]; o.w = rr[3];
  *(uint4*)(g + m * INNER_ + j) = o;
}

// ---------------- instance norm ----------------
__global__ __launch_bounds__(256) void inorm_stats(const float* __restrict__ y,
                                                   float* __restrict__ stats) {
  int b = blockIdx.x, dc = blockIdx.y;
  int dl = threadIdx.x & 63, sl = threadIdx.x >> 6;
  int d = dc * 64 + dl;
  const float* yb = y + (size_t)b * S_ * D_ + d;
  float s1 = 0.f, s2 = 0.f;
  for (int i = 0; i < 256; i++) {
    int s = sl * 256 + i;
    float v = yb[(size_t)s * D_];
    s1 += v; s2 += v * v;
  }
  __shared__ float r1[256], r2[256];
  r1[threadIdx.x] = s1; r2[threadIdx.x] = s2;
  __syncthreads();
  if (sl == 0) {
    s1 = r1[dl] + r1[dl + 64] + r1[dl + 128] + r1[dl + 192];
    s2 = r2[dl] + r2[dl + 64] + r2[dl + 128] + r2[dl + 192];
    stats[((size_t)b * D_ + d) * 2]     = s1;
    stats[((size_t)b * D_ + d) * 2 + 1] = s2;
  }
}

__global__ __launch_bounds__(256) void inorm_apply(const float* __restrict__ y,
                                                   const float* __restrict__ stats,
                                                   const float* __restrict__ w,
                                                   const float* __restrict__ bias,
                                                   float* __restrict__ out) {
  int row = blockIdx.x;
  int b = row >> 10;
  int tid = threadIdx.x;
  #pragma unroll
  for (int i = 0; i < 2; i++) {
    int d = tid + i * 256;
    float m  = stats[((size_t)b * D_ + d) * 2]     * (1.f / 1024.f);
    float v2 = stats[((size_t)b * D_ + d) * 2 + 1] * (1.f / 1024.f);
    float rs = rsqrtf(v2 - m * m + 1e-5f);
    float v = y[(size_t)row * D_ + d];
    out[(size_t)row * D_ + d] = (v - m) * rs * w[d] + bias[d];
  }
}

// ---------------- launch ----------------
extern "C" void kernel_launch(void* const* d_in, const int* in_sizes, int n_in,
                              void* d_out, int out_size, void* d_ws, size_t ws_size,
                              hipStream_t stream) {
  const float* x    = (const float*)d_in[0];
  const float* Wq   = (const float*)d_in[1];
  const float* bq   = (const float*)d_in[2];
  const float* Wkv  = (const float*)d_in[3];
  const float* bkv  = (const float*)d_in[4];
  const float* Wo   = (const float*)d_in[5];
  const float* bo   = (const float*)d_in[6];
  const float* rmsw = (const float*)d_in[7];
  const float* l1   = (const float*)d_in[8];
  const float* l2   = (const float*)d_in[9];
  const float* l3   = (const float*)d_in[10];
  const float* inw  = (const float*)d_in[11];
  const float* inb  = (const float*)d_in[12];
  float* out = (float*)d_out;

  char* ws = (char*)d_ws;
  size_t off = 0;
  auto alloc = [&](size_t n) { char* p = ws + off; off += (n + 255) & ~(size_t)255; return p; };
  u16*  xb   = (u16*) alloc((size_t)M_ * D_ * 2);
  u16*  Wt1  = (u16*) alloc((size_t)1536 * 512 * 2);
  u16*  Wot  = (u16*) alloc((size_t)512 * 512 * 2);
  u16*  W12t = (u16*) alloc((size_t)3072 * 512 * 2);
  u16*  l3t  = (u16*) alloc((size_t)512 * 1536 * 2);
  u16*  qb   = (u16*) alloc((size_t)M_ * D_ * 2);      // f16 [B,H,S,DH]
  u16*  kb   = (u16*) alloc((size_t)M_ * D_ * 2);      // f16 [B,H,S,DH]
  u16*  vtb  = (u16*) alloc((size_t)M_ * D_ * 2);      // f16 [B,H,DH,S]
  u16*  attn = (u16*) alloc((size_t)M_ * D_ * 2);      // bf16 [B,S,D]
  float* tmpF = (float*)alloc((size_t)M_ * D_ * 4);
  u16*  hhat = (u16*) alloc((size_t)M_ * D_ * 2);
  u16*  ab   = (u16*) alloc((size_t)M_ * 3072 * 2);
  u16*  g    = (u16*) alloc((size_t)M_ * INNER_ * 2);
  float* stats = (float*)alloc((size_t)B_ * D_ * 2 * 4);

  transpose_all<<<832, 256, 0, stream>>>(Wq, Wkv, Wo, l1, l2, l3, Wt1, Wot, W12t, l3t);
  prep_kernel<<<2048, 256, 0, stream>>>(x, bo, xb, tmpF);

  gemm_bt<1><<<dim3(12, 32), 256, 0, stream>>>(xb, Wt1, M_, 1536, 512,
      bq, bkv, nullptr, qb, kb, vtb);

  attn_kernel<<<2048, 256, 0, stream>>>(qb, kb, vtb, attn);

  // out proj: tmpF (= x + bo) += attn @ Wo^T, split-K=2
  gemm_sk<<<dim3(4, 32, 2), 256, 0, stream>>>(attn, Wot, 512, 512, 256, tmpF);

  rms_kernel<<<4096, 128, 0, stream>>>(tmpF, rmsw, hhat);   // tmpF := h_hat f32 in-place

  gemm_bt<3><<<dim3(24, 32), 256, 0, stream>>>(hhat, W12t, M_, 3072, 512,
      nullptr, nullptr, ab, nullptr, nullptr, nullptr);

  silu_mul_kernel<<<3072, 256, 0, stream>>>(ab, g);

  // FFN down: tmpF (= h_hat) += g @ l3t^T, split-K=2
  gemm_sk<<<dim3(4, 32, 2), 256, 0, stream>>>(g, l3t, 512, 1536, 768, tmpF);

  inorm_stats<<<dim3(4, 8), 256, 0, stream>>>(tmpF, stats);
  inorm_apply<<<4096, 256, 0, stream>>>(tmpF, stats, inw, inb, out);
}

// Round 6
// 275.497 us; speedup vs baseline: 1.1356x; 1.1356x over previous
//
#include <hip/hip_runtime.h>
#include <stdint.h>

#define B_ 4
#define S_ 1024
#define D_ 512
#define H_ 8
#define DH_ 64
#define INNER_ 1536
#define M_ (B_*S_)   // 4096

typedef unsigned short u16;
typedef __attribute__((ext_vector_type(8))) short sh8;      // 8 bf16
typedef __attribute__((ext_vector_type(8))) _Float16 h8;    // 8 f16
typedef __attribute__((ext_vector_type(4))) _Float16 h4;    // 4 f16
typedef __attribute__((ext_vector_type(2))) _Float16 h2f;   // 2 f16
typedef __attribute__((ext_vector_type(2))) unsigned short us2;
typedef __attribute__((ext_vector_type(4))) float f32x4;

typedef __attribute__((address_space(1))) const void cgv;
typedef __attribute__((address_space(3))) void lv;
__device__ __forceinline__ void gl_lds16(const void* g, void* l) {
  __builtin_amdgcn_global_load_lds((cgv*)g, (lv*)l, 16, 0, 0);
}

__device__ __forceinline__ float bf2f(u16 u) {
  union { unsigned int i; float f; } v; v.i = ((unsigned int)u) << 16; return v.f;
}
__device__ __forceinline__ u16 f2bf(float f) {
  union { float f; unsigned int i; } v; v.f = f;
  unsigned int u = v.i;
  return (u16)((u + 0x7FFFu + ((u >> 16) & 1u)) >> 16);
}
__device__ __forceinline__ u16 f2h(float f) {
  _Float16 h = (_Float16)f;
  return *(u16*)&h;
}
__device__ __forceinline__ float h_lo(uint32_t v) {
  h2f h = __builtin_bit_cast(h2f, v); return (float)h[0];
}
__device__ __forceinline__ float h_hi(uint32_t v) {
  h2f h = __builtin_bit_cast(h2f, v); return (float)h[1];
}

// ---------------- fp32 -> bf16 convert ----------------
__global__ __launch_bounds__(256) void f2b_kernel(const float* __restrict__ in,
                                                  u16* __restrict__ out) {
  int i = (blockIdx.x * 256 + threadIdx.x) * 4;
  float4 v = *(const float4*)(in + i);
  uint2 o;
  o.x = (unsigned int)f2bf(v.x) | ((unsigned int)f2bf(v.y) << 16);
  o.y = (unsigned int)f2bf(v.z) | ((unsigned int)f2bf(v.w) << 16);
  *(uint2*)(out + i) = o;
}

// ---------------- all weight transposes in one launch ----------------
// l1/l2 are written INTERLEAVED into W12t: l1 col j -> row 2j, l2 col j -> row 2j+1.
__global__ __launch_bounds__(256) void transpose_all(
    const float* __restrict__ Wq, const float* __restrict__ Wkv,
    const float* __restrict__ Wo, const float* __restrict__ l1,
    const float* __restrict__ l2, const float* __restrict__ l3,
    u16* __restrict__ Wt1, u16* __restrict__ Wot,
    u16* __restrict__ W12t, u16* __restrict__ l3t)
{
  int i = blockIdx.x;
  const float* in; u16* outp; int K, N, bx, by, rs = 1, ra = 0;
  if (i < 64)       { in = Wq;  outp = Wt1;              K = 512;  N = 512;           bx = i & 7;  by = i >> 3; }
  else if (i < 192) { in = Wkv; outp = Wt1 + 512 * 512;  K = 512;  N = 1024; i -= 64; bx = i & 15; by = i >> 4; }
  else if (i < 256) { in = Wo;  outp = Wot;              K = 512;  N = 512;  i -= 192; bx = i & 7;  by = i >> 3; }
  else if (i < 448) { in = l1;  outp = W12t;             K = 512;  N = 1536; i -= 256; bx = i % 24; by = i / 24; rs = 2; ra = 0; }
  else if (i < 640) { in = l2;  outp = W12t;             K = 512;  N = 1536; i -= 448; bx = i % 24; by = i / 24; rs = 2; ra = 1; }
  else              { in = l3;  outp = l3t;              K = 1536; N = 512;  i -= 640; bx = i & 7;  by = i >> 3; }

  __shared__ u16 tile[64][65];
  int tx = threadIdx.x & 63, ty = threadIdx.x >> 6;
  int n0 = bx * 64, k0 = by * 64;
  #pragma unroll
  for (int t = 0; t < 16; t++) {
    int k = ty + t * 4;
    tile[k][tx] = f2bf(in[(size_t)(k0 + k) * N + n0 + tx]);
  }
  __syncthreads();
  #pragma unroll
  for (int t = 0; t < 16; t++) {
    int n = ty + t * 4;
    outp[(size_t)((n0 + n) * rs + ra) * K + k0 + tx] = tile[tx][n];
  }
}

// ---------------- 128x128 GEMM, glds staging ----------------
// EPI 1: qkv scatter (+biases), q/k/v stored f16
// EPI 3: silu-fused FFN-up: Bt has interleaved l1/l2 rows; writes g[M, N/2] bf16
template<int EPI>
__global__ __launch_bounds__(256) void gemm_bt(
    const u16* __restrict__ A, const u16* __restrict__ Bt,
    int M, int N, int K,
    const float* __restrict__ bias0, const float* __restrict__ bias1,
    u16* __restrict__ outU,
    u16* __restrict__ qo, u16* __restrict__ ko_, u16* __restrict__ vto)
{
  __shared__ u16 As[128 * 32];
  __shared__ u16 Bs[128 * 32];
  int tid = threadIdx.x;
  int gx = blockIdx.x, gy = blockIdx.y;
  int l = tid & 63, w = tid >> 6;
  int l15 = l & 15, quad = l >> 4;
  int wm = (w >> 1) * 64, wn = (w & 1) * 64;
  f32x4 acc[4][4] = {};

  const u16* Ag = A  + (size_t)(gy * 128 + (tid >> 2)) * K + (tid & 3) * 8;
  const u16* Bg = Bt + (size_t)(gx * 128 + (tid >> 2)) * K + (tid & 3) * 8;

  for (int ko = 0; ko < K; ko += 32) {
    __syncthreads();
    gl_lds16(Ag + ko,                  &As[tid * 8]);
    gl_lds16(Ag + (size_t)64 * K + ko, &As[2048 + tid * 8]);
    gl_lds16(Bg + ko,                  &Bs[tid * 8]);
    gl_lds16(Bg + (size_t)64 * K + ko, &Bs[2048 + tid * 8]);
    __syncthreads();
    sh8 af[4], bfr[4];
    #pragma unroll
    for (int mi = 0; mi < 4; mi++)
      af[mi] = *(const sh8*)&As[(wm + mi * 16 + l15) * 32 + quad * 8];
    #pragma unroll
    for (int ni = 0; ni < 4; ni++)
      bfr[ni] = *(const sh8*)&Bs[(wn + ni * 16 + l15) * 32 + quad * 8];
    #pragma unroll
    for (int mi = 0; mi < 4; mi++)
      #pragma unroll
      for (int ni = 0; ni < 4; ni++)
        acc[mi][ni] = __builtin_amdgcn_mfma_f32_16x16x32_bf16(af[mi], bfr[ni], acc[mi][ni], 0, 0, 0);
  }

  #pragma unroll
  for (int mi = 0; mi < 4; mi++) {
    #pragma unroll
    for (int ni = 0; ni < 4; ni++) {
      #pragma unroll
      for (int r = 0; r < 4; r++) {
        int grow = gy * 128 + wm + mi * 16 + quad * 4 + r;
        int gcol = gx * 128 + wn + ni * 16 + l15;
        float v = acc[mi][ni][r];
        if (EPI == 1) {
          int b = grow >> 10, s = grow & 1023;
          if (gcol < 512) {
            int h = gcol >> 6, dh = gcol & 63;
            qo[(((size_t)b * H_ + h) * S_ + s) * DH_ + dh] = f2h(v + bias0[gcol]);
          } else {
            int n2 = gcol - 512;
            int two = n2 >> 9, h = (n2 >> 6) & 7, dh = n2 & 63;
            float vv = v + bias1[n2];
            if (two == 0) ko_[(((size_t)b * H_ + h) * S_ + s) * DH_ + dh] = f2h(vv);
            else          vto[(((size_t)b * H_ + h) * DH_ + dh) * S_ + s] = f2h(vv);
          }
        } else {
          // even gcol = a (l1), odd gcol = b (l2); pair lives in adjacent lanes
          float vp = __shfl_xor(v, 1);
          if ((l15 & 1) == 0) {
            float a = v, b = vp;
            float gv = a / (1.f + __expf(-a)) * b;
            outU[(size_t)grow * (N >> 1) + (gcol >> 1)] = f2bf(gv);
          }
        }
      }
    }
  }
}

// ---------------- 64x64 GEMM for small-N layers (512 blocks) ----------------
// EPI 2: +bias0 +auxF(fp32) -> outF ; EPI 4: +auxH(bf16) -> outF
template<int EPI>
__global__ __launch_bounds__(256) void gemm64(
    const u16* __restrict__ A, const u16* __restrict__ Bt,
    int M, int N, int K,
    const float* __restrict__ bias0, const float* __restrict__ auxF,
    const u16* __restrict__ auxH, float* __restrict__ outF)
{
  __shared__ u16 As[64 * 32];
  __shared__ u16 Bs[64 * 32];
  int tid = threadIdx.x;
  int gx = blockIdx.x, gy = blockIdx.y;
  int l = tid & 63, w = tid >> 6;
  int l15 = l & 15, quad = l >> 4;
  int wm = (w >> 1) * 32, wn = (w & 1) * 32;
  f32x4 acc[2][2] = {};

  const u16* Ag = A  + (size_t)(gy * 64 + (tid >> 2)) * K + (tid & 3) * 8;
  const u16* Bg = Bt + (size_t)(gx * 64 + (tid >> 2)) * K + (tid & 3) * 8;

  for (int ko = 0; ko < K; ko += 32) {
    __syncthreads();
    gl_lds16(Ag + ko, &As[tid * 8]);
    gl_lds16(Bg + ko, &Bs[tid * 8]);
    __syncthreads();
    sh8 af[2], bfr[2];
    #pragma unroll
    for (int mi = 0; mi < 2; mi++)
      af[mi] = *(const sh8*)&As[(wm + mi * 16 + l15) * 32 + quad * 8];
    #pragma unroll
    for (int ni = 0; ni < 2; ni++)
      bfr[ni] = *(const sh8*)&Bs[(wn + ni * 16 + l15) * 32 + quad * 8];
    #pragma unroll
    for (int mi = 0; mi < 2; mi++)
      #pragma unroll
      for (int ni = 0; ni < 2; ni++)
        acc[mi][ni] = __builtin_amdgcn_mfma_f32_16x16x32_bf16(af[mi], bfr[ni], acc[mi][ni], 0, 0, 0);
  }

  #pragma unroll
  for (int mi = 0; mi < 2; mi++) {
    #pragma unroll
    for (int ni = 0; ni < 2; ni++) {
      #pragma unroll
      for (int r = 0; r < 4; r++) {
        int grow = gy * 64 + wm + mi * 16 + quad * 4 + r;
        int gcol = gx * 64 + wn + ni * 16 + l15;
        float v = acc[mi][ni][r];
        if (EPI == 2) v += bias0[gcol] + auxF[(size_t)grow * N + gcol];
        else          v += bf2f(auxH[(size_t)grow * N + gcol]);
        outF[(size_t)grow * N + gcol] = v;
      }
    }
  }
}

// ---------------- sparse attention: packed-key bisect, 32KB swizzled LDS, no spill ----------------
__global__ __launch_bounds__(256, 4) void attn_kernel(
    const u16* __restrict__ q, const u16* __restrict__ kk,
    const u16* __restrict__ vt, u16* __restrict__ attn)
{
  __shared__ u16 scb[16 * 1024];   // 32 KB; rows of 1024 halves, 4-half chunks XOR-swizzled

  int tid = threadIdx.x;
  int l = tid & 63, w = tid >> 6;
  int l15 = l & 15, quad = l >> 4;
  int blk = blockIdx.x;
  int bh = blk >> 6;             // b*8+h
  int r0 = (blk & 63) << 4;      // query tile start

  const u16* qb = q  + ((size_t)bh * S_ + r0) * DH_;
  const u16* kb = kk + (size_t)bh * S_ * DH_;
  const u16* vb = vt + (size_t)bh * DH_ * S_;

  h8 aq0 = *(const h8*)(qb + l15 * DH_ + quad * 8);
  h8 aq1 = *(const h8*)(qb + l15 * DH_ + 32 + quad * 8);

  // ---- phase A: scores = (K Q^T)/8 -> LDS f16, swizzled chunks
  #pragma unroll
  for (int i = 0; i < 16; i++) {
    int t0 = ((i << 2) | w) << 4;
    const u16* kr = kb + (size_t)(t0 + l15) * DH_;
    h8 bk0 = *(const h8*)(kr + quad * 8);
    h8 bk1 = *(const h8*)(kr + 32 + quad * 8);
    f32x4 s4 = {};
    s4 = __builtin_amdgcn_mfma_f32_16x16x32_f16(bk0, aq0, s4, 0, 0, 0);
    s4 = __builtin_amdgcn_mfma_f32_16x16x32_f16(bk1, aq1, s4, 0, 0, 0);
    h4 hv;
    #pragma unroll
    for (int r = 0; r < 4; r++) hv[r] = (_Float16)(s4[r] * 0.125f);
    int cc = ((t0 >> 2) + quad) ^ l15;   // chunk index, swizzled
    *(h4*)(scb + l15 * 1024 + (cc << 2)) = hv;
  }
  __syncthreads();   // B1

  // ---- phase B: registers only. 64 scores per thread as 32 packed words.
  int row = tid >> 4, l16 = tid & 15;
  u16* rowp = scb + row * 1024;
  uint32_t kv[32];
  float Z1 = 0.f;
  #pragma unroll
  for (int u = 0; u < 16; u++) {
    int cc = (l16 + (u << 4)) ^ row;
    uint2 rr = *(const uint2*)(rowp + (cc << 2));
    uint32_t v0 = rr.x, v1 = rr.y;
    Z1 += __expf(h_lo(v0)) + __expf(h_hi(v0)) + __expf(h_lo(v1)) + __expf(h_hi(v1));
    uint32_t m0 = v0 & 0x80008000u;
    uint32_t m1 = v1 & 0x80008000u;
    kv[2 * u]     = v0 ^ (0x80008000u | ((m0 >> 15) * 0x7FFFu));  // monotone 16-bit keys
    kv[2 * u + 1] = v1 ^ (0x80008000u | ((m1 >> 15) * 0x7FFFu));
  }
  #pragma unroll
  for (int d = 1; d < 16; d <<= 1) Z1 += __shfl_xor(Z1, d);
  float invZ = 1.0f / Z1;

  // bisect top 12 bits of the key threshold: largest T with count(key>=T) >= 512
  us2 onep; onep[0] = 1; onep[1] = 1;
  uint32_t lo = 0;
  #pragma unroll
  for (int bit = 15; bit >= 4; bit--) {
    uint32_t cand = lo | (1u << bit);
    uint32_t tm1 = cand - 1u;
    us2 tp; tp[0] = (unsigned short)tm1; tp[1] = (unsigned short)tm1;
    uint32_t acc = 0;
    #pragma unroll
    for (int t = 0; t < 32; t++) {
      us2 a = __builtin_bit_cast(us2, kv[t]);
      us2 d = __builtin_elementwise_sub_sat(a, tp);   // v_pk_sub_u16 clamp
      d = __builtin_elementwise_min(d, onep);         // v_pk_min_u16
      acc += __builtin_bit_cast(uint32_t, d);
    }
    uint32_t cnt = (acc & 0xFFFFu) + (acc >> 16);
    #pragma unroll
    for (int d2 = 1; d2 < 16; d2 <<= 1) cnt += __shfl_xor(cnt, d2);
    if (cnt >= 512u) lo = cand;
  }

  // coefficients c = kept ? exp(w) : 1, packed f16 back into kv
  float Z2 = 0.f;
  #pragma unroll
  for (int t = 0; t < 32; t++) {
    uint32_t km = kv[t];
    uint32_t nb = (~km) & 0x80008000u;
    uint32_t raw = km ^ (0x80008000u | ((nb >> 15) * 0x7FFFu));
    float w0 = __expf(h_lo(raw)) * invZ;
    float w1 = __expf(h_hi(raw)) * invZ;
    float c0 = ((km & 0xFFFFu) >= lo) ? __expf(w0) : 1.0f;
    float c1 = ((km >> 16)     >= lo) ? __expf(w1) : 1.0f;
    Z2 += c0 + c1;
    h2f cp; cp[0] = (_Float16)c0; cp[1] = (_Float16)c1;
    kv[t] = __builtin_bit_cast(uint32_t, cp);
  }
  #pragma unroll
  for (int d = 1; d < 16; d <<= 1) Z2 += __shfl_xor(Z2, d);
  _Float16 zh = (_Float16)(1.0f / Z2);
  h2f zp; zp[0] = zh; zp[1] = zh;

  // scale by 1/Z2 and store back to the same swizzled slots
  #pragma unroll
  for (int u = 0; u < 16; u++) {
    h2f a = __builtin_bit_cast(h2f, kv[2 * u]) * zp;
    h2f b = __builtin_bit_cast(h2f, kv[2 * u + 1]) * zp;
    uint2 ov;
    ov.x = __builtin_bit_cast(uint32_t, a);
    ov.y = __builtin_bit_cast(uint32_t, b);
    int cc = (l16 + (u << 4)) ^ row;
    *(uint2*)(rowp + (cc << 2)) = ov;
  }
  __syncthreads();   // B2

  // ---- phase E: o = c' @ V via f16 MFMA (coefficients already carry 1/Z2)
  int n0 = w << 4;
  const u16* crow = scb + l15 * 1024;
  f32x4 oacc = {};
  #pragma unroll
  for (int kt = 0; kt < 32; kt++) {
    int c0 = ((kt << 3) + (quad << 1)) ^ l15;
    int c1 = ((kt << 3) + (quad << 1) + 1) ^ l15;
    uint2 u0 = *(const uint2*)(crow + (c0 << 2));
    uint2 u1 = *(const uint2*)(crow + (c1 << 2));
    h8 ca;
    ((uint2*)&ca)[0] = u0;
    ((uint2*)&ca)[1] = u1;
    h8 vv = *(const h8*)(vb + (size_t)(n0 + l15) * S_ + kt * 32 + quad * 8);
    oacc = __builtin_amdgcn_mfma_f32_16x16x32_f16(ca, vv, oacc, 0, 0, 0);
  }
  int b = bh >> 3, hh = bh & 7;
  #pragma unroll
  for (int r = 0; r < 4; r++) {
    int rr = quad * 4 + r;
    attn[((size_t)b * S_ + r0 + rr) * D_ + hh * DH_ + n0 + l15] = f2bf(oacc[r]);
  }
}

// ---------------- RMS norm over D per row: fp32 in, bf16 out ----------------
__global__ __launch_bounds__(128) void rms_kernel(const float* __restrict__ in,
                                                  const float* __restrict__ w,
                                                  u16* __restrict__ out) {
  int row = blockIdx.x;
  int tid = threadIdx.x;
  const float* r = in + (size_t)row * D_;
  float v0 = r[tid], v1 = r[tid + 128], v2 = r[tid + 256], v3 = r[tid + 384];
  float s = v0 * v0 + v1 * v1 + v2 * v2 + v3 * v3;
  #pragma unroll
  for (int d = 1; d < 64; d <<= 1) s += __shfl_xor(s, d);
  __shared__ float red[2];
  if ((tid & 63) == 0) red[tid >> 6] = s;
  __syncthreads();
  s = red[0] + red[1];
  float rs = rsqrtf(s * (1.0f / 512.0f) + 1e-6f);
  out[(size_t)row * D_ + tid      ] = f2bf(v0 * rs * w[tid      ]);
  out[(size_t)row * D_ + tid + 128] = f2bf(v1 * rs * w[tid + 128]);
  out[(size_t)row * D_ + tid + 256] = f2bf(v2 * rs * w[tid + 256]);
  out[(size_t)row * D_ + tid + 384] = f2bf(v3 * rs * w[tid + 384]);
}

// ---------------- instance norm: one-pass stats, then apply ----------------
__global__ __launch_bounds__(256) void inorm_stats(const float* __restrict__ y,
                                                   float* __restrict__ stats) {
  int b = blockIdx.x, dc = blockIdx.y;
  int dl = threadIdx.x & 63, sl = threadIdx.x >> 6;
  int d = dc * 64 + dl;
  const float* yb = y + (size_t)b * S_ * D_ + d;
  float s1 = 0.f, s2 = 0.f;
  for (int i = 0; i < 256; i++) {
    int s = sl * 256 + i;
    float v = yb[(size_t)s * D_];
    s1 += v; s2 += v * v;
  }
  __shared__ float r1[256], r2[256];
  r1[threadIdx.x] = s1; r2[threadIdx.x] = s2;
  __syncthreads();
  if (sl == 0) {
    s1 = r1[dl] + r1[dl + 64] + r1[dl + 128] + r1[dl + 192];
    s2 = r2[dl] + r2[dl + 64] + r2[dl + 128] + r2[dl + 192];
    stats[((size_t)b * D_ + d) * 2]     = s1;
    stats[((size_t)b * D_ + d) * 2 + 1] = s2;
  }
}

__global__ __launch_bounds__(256) void inorm_apply(const float* __restrict__ y,
                                                   const float* __restrict__ stats,
                                                   const float* __restrict__ w,
                                                   const float* __restrict__ bias,
                                                   float* __restrict__ out) {
  int row = blockIdx.x;
  int b = row >> 10;
  int tid = threadIdx.x;
  #pragma unroll
  for (int i = 0; i < 2; i++) {
    int d = tid + i * 256;
    float m  = stats[((size_t)b * D_ + d) * 2]     * (1.f / 1024.f);
    float v2 = stats[((size_t)b * D_ + d) * 2 + 1] * (1.f / 1024.f);
    float rs = rsqrtf(v2 - m * m + 1e-5f);
    float v = y[(size_t)row * D_ + d];
    out[(size_t)row * D_ + d] = (v - m) * rs * w[d] + bias[d];
  }
}

// ---------------- launch ----------------
extern "C" void kernel_launch(void* const* d_in, const int* in_sizes, int n_in,
                              void* d_out, int out_size, void* d_ws, size_t ws_size,
                              hipStream_t stream) {
  const float* x    = (const float*)d_in[0];
  const float* Wq   = (const float*)d_in[1];
  const float* bq   = (const float*)d_in[2];
  const float* Wkv  = (const float*)d_in[3];
  const float* bkv  = (const float*)d_in[4];
  const float* Wo   = (const float*)d_in[5];
  const float* bo   = (const float*)d_in[6];
  const float* rmsw = (const float*)d_in[7];
  const float* l1   = (const float*)d_in[8];
  const float* l2   = (const float*)d_in[9];
  const float* l3   = (const float*)d_in[10];
  const float* inw  = (const float*)d_in[11];
  const float* inb  = (const float*)d_in[12];
  float* out = (float*)d_out;

  char* ws = (char*)d_ws;
  size_t off = 0;
  auto alloc = [&](size_t n) { char* p = ws + off; off += (n + 255) & ~(size_t)255; return p; };
  u16*  xb   = (u16*) alloc((size_t)M_ * D_ * 2);
  u16*  Wt1  = (u16*) alloc((size_t)1536 * 512 * 2);
  u16*  Wot  = (u16*) alloc((size_t)512 * 512 * 2);
  u16*  W12t = (u16*) alloc((size_t)3072 * 512 * 2);   // interleaved l1/l2
  u16*  l3t  = (u16*) alloc((size_t)512 * 1536 * 2);
  u16*  qb   = (u16*) alloc((size_t)M_ * D_ * 2);      // f16 [B,H,S,DH]
  u16*  kb   = (u16*) alloc((size_t)M_ * D_ * 2);      // f16 [B,H,S,DH]
  u16*  vtb  = (u16*) alloc((size_t)M_ * D_ * 2);      // f16 [B,H,DH,S]
  u16*  attn = (u16*) alloc((size_t)M_ * D_ * 2);      // bf16 [B,S,D]
  float* tmpF = (float*)alloc((size_t)M_ * D_ * 4);
  u16*  hhat = (u16*) alloc((size_t)M_ * D_ * 2);
  u16*  g    = (u16*) alloc((size_t)M_ * INNER_ * 2);
  float* stats = (float*)alloc((size_t)B_ * D_ * 2 * 4);

  transpose_all<<<832, 256, 0, stream>>>(Wq, Wkv, Wo, l1, l2, l3, Wt1, Wot, W12t, l3t);
  f2b_kernel<<<2048, 256, 0, stream>>>(x, xb);

  gemm_bt<1><<<dim3(12, 32), 256, 0, stream>>>(xb, Wt1, M_, 1536, 512,
      bq, bkv, nullptr, qb, kb, vtb);

  attn_kernel<<<2048, 256, 0, stream>>>(qb, kb, vtb, attn);

  gemm64<2><<<dim3(8, 64), 256, 0, stream>>>(attn, Wot, M_, 512, 512,
      bo, x, nullptr, tmpF);

  rms_kernel<<<4096, 128, 0, stream>>>(tmpF, rmsw, hhat);

  // FFN up + silu fused: writes g [M, 1536] directly
  gemm_bt<3><<<dim3(24, 32), 256, 0, stream>>>(hhat, W12t, M_, 3072, 512,
      nullptr, nullptr, g, nullptr, nullptr, nullptr);

  gemm64<4><<<dim3(8, 64), 256, 0, stream>>>(g, l3t, M_, 512, 1536,
      nullptr, nullptr, hhat, tmpF);

  inorm_stats<<<dim3(4, 8), 256, 0, stream>>>(tmpF, stats);
  inorm_apply<<<4096, 256, 0, stream>>>(tmpF, stats, inw, inb, out);
}

// Round 7
// 265.432 us; speedup vs baseline: 1.1786x; 1.0379x over previous
//
#include <hip/hip_runtime.h>
#include <stdint.h>

#define B_ 4
#define S_ 1024
#define D_ 512
#define H_ 8
#define DH_ 64
#define INNER_ 1536
#define M_ (B_*S_)   // 4096

typedef unsigned short u16;
typedef __attribute__((ext_vector_type(8))) short sh8;      // 8 bf16
typedef __attribute__((ext_vector_type(8))) _Float16 h8;    // 8 f16
typedef __attribute__((ext_vector_type(4))) _Float16 h4;    // 4 f16
typedef __attribute__((ext_vector_type(2))) _Float16 h2f;   // 2 f16
typedef __attribute__((ext_vector_type(2))) unsigned short us2;
typedef __attribute__((ext_vector_type(4))) float f32x4;

typedef __attribute__((address_space(1))) const void cgv;
typedef __attribute__((address_space(3))) void lv;
__device__ __forceinline__ void gl_lds16(const void* g, void* l) {
  __builtin_amdgcn_global_load_lds((cgv*)g, (lv*)l, 16, 0, 0);
}

__device__ __forceinline__ float bf2f(u16 u) {
  union { unsigned int i; float f; } v; v.i = ((unsigned int)u) << 16; return v.f;
}
__device__ __forceinline__ u16 f2bf(float f) {
  union { float f; unsigned int i; } v; v.f = f;
  unsigned int u = v.i;
  return (u16)((u + 0x7FFFu + ((u >> 16) & 1u)) >> 16);
}
__device__ __forceinline__ u16 f2h(float f) {
  _Float16 h = (_Float16)f;
  return *(u16*)&h;
}
__device__ __forceinline__ float h_lo(uint32_t v) {
  h2f h = __builtin_bit_cast(h2f, v); return (float)h[0];
}
__device__ __forceinline__ float h_hi(uint32_t v) {
  h2f h = __builtin_bit_cast(h2f, v); return (float)h[1];
}

// ---------------- fp32 -> bf16 convert ----------------
__global__ __launch_bounds__(256) void f2b_kernel(const float* __restrict__ in,
                                                  u16* __restrict__ out) {
  int i = (blockIdx.x * 256 + threadIdx.x) * 4;
  float4 v = *(const float4*)(in + i);
  uint2 o;
  o.x = (unsigned int)f2bf(v.x) | ((unsigned int)f2bf(v.y) << 16);
  o.y = (unsigned int)f2bf(v.z) | ((unsigned int)f2bf(v.w) << 16);
  *(uint2*)(out + i) = o;
}

// ---------------- all weight transposes in one launch ----------------
// l1/l2 interleaved into W12t: l1 col j -> row 2j, l2 col j -> row 2j+1.
__global__ __launch_bounds__(256) void transpose_all(
    const float* __restrict__ Wq, const float* __restrict__ Wkv,
    const float* __restrict__ Wo, const float* __restrict__ l1,
    const float* __restrict__ l2, const float* __restrict__ l3,
    u16* __restrict__ Wt1, u16* __restrict__ Wot,
    u16* __restrict__ W12t, u16* __restrict__ l3t)
{
  int i = blockIdx.x;
  const float* in; u16* outp; int K, N, bx, by, rs = 1, ra = 0;
  if (i < 64)       { in = Wq;  outp = Wt1;              K = 512;  N = 512;           bx = i & 7;  by = i >> 3; }
  else if (i < 192) { in = Wkv; outp = Wt1 + 512 * 512;  K = 512;  N = 1024; i -= 64; bx = i & 15; by = i >> 4; }
  else if (i < 256) { in = Wo;  outp = Wot;              K = 512;  N = 512;  i -= 192; bx = i & 7;  by = i >> 3; }
  else if (i < 448) { in = l1;  outp = W12t;             K = 512;  N = 1536; i -= 256; bx = i % 24; by = i / 24; rs = 2; ra = 0; }
  else if (i < 640) { in = l2;  outp = W12t;             K = 512;  N = 1536; i -= 448; bx = i % 24; by = i / 24; rs = 2; ra = 1; }
  else              { in = l3;  outp = l3t;              K = 1536; N = 512;  i -= 640; bx = i & 7;  by = i >> 3; }

  __shared__ u16 tile[64][65];
  int tx = threadIdx.x & 63, ty = threadIdx.x >> 6;
  int n0 = bx * 64, k0 = by * 64;
  #pragma unroll
  for (int t = 0; t < 16; t++) {
    int k = ty + t * 4;
    tile[k][tx] = f2bf(in[(size_t)(k0 + k) * N + n0 + tx]);
  }
  __syncthreads();
  #pragma unroll
  for (int t = 0; t < 16; t++) {
    int n = ty + t * 4;
    outp[(size_t)((n0 + n) * rs + ra) * K + k0 + tx] = tile[tx][n];
  }
}

// ---------------- 128x128 GEMM, glds staging ----------------
// EPI 1: qkv scatter (+biases), q/k/v stored f16
// EPI 3: silu-fused FFN-up: interleaved l1/l2 cols; writes g[M, N/2] bf16
template<int EPI>
__global__ __launch_bounds__(256) void gemm_bt(
    const u16* __restrict__ A, const u16* __restrict__ Bt,
    int M, int N, int K,
    const float* __restrict__ bias0, const float* __restrict__ bias1,
    u16* __restrict__ outU,
    u16* __restrict__ qo, u16* __restrict__ ko_, u16* __restrict__ vto)
{
  __shared__ u16 As[128 * 32];
  __shared__ u16 Bs[128 * 32];
  int tid = threadIdx.x;
  int gx = blockIdx.x, gy = blockIdx.y;
  int l = tid & 63, w = tid >> 6;
  int l15 = l & 15, quad = l >> 4;
  int wm = (w >> 1) * 64, wn = (w & 1) * 64;
  f32x4 acc[4][4] = {};

  const u16* Ag = A  + (size_t)(gy * 128 + (tid >> 2)) * K + (tid & 3) * 8;
  const u16* Bg = Bt + (size_t)(gx * 128 + (tid >> 2)) * K + (tid & 3) * 8;

  for (int ko = 0; ko < K; ko += 32) {
    __syncthreads();
    gl_lds16(Ag + ko,                  &As[tid * 8]);
    gl_lds16(Ag + (size_t)64 * K + ko, &As[2048 + tid * 8]);
    gl_lds16(Bg + ko,                  &Bs[tid * 8]);
    gl_lds16(Bg + (size_t)64 * K + ko, &Bs[2048 + tid * 8]);
    __syncthreads();
    sh8 af[4], bfr[4];
    #pragma unroll
    for (int mi = 0; mi < 4; mi++)
      af[mi] = *(const sh8*)&As[(wm + mi * 16 + l15) * 32 + quad * 8];
    #pragma unroll
    for (int ni = 0; ni < 4; ni++)
      bfr[ni] = *(const sh8*)&Bs[(wn + ni * 16 + l15) * 32 + quad * 8];
    #pragma unroll
    for (int mi = 0; mi < 4; mi++)
      #pragma unroll
      for (int ni = 0; ni < 4; ni++)
        acc[mi][ni] = __builtin_amdgcn_mfma_f32_16x16x32_bf16(af[mi], bfr[ni], acc[mi][ni], 0, 0, 0);
  }

  #pragma unroll
  for (int mi = 0; mi < 4; mi++) {
    #pragma unroll
    for (int ni = 0; ni < 4; ni++) {
      #pragma unroll
      for (int r = 0; r < 4; r++) {
        int grow = gy * 128 + wm + mi * 16 + quad * 4 + r;
        int gcol = gx * 128 + wn + ni * 16 + l15;
        float v = acc[mi][ni][r];
        if (EPI == 1) {
          int b = grow >> 10, s = grow & 1023;
          if (gcol < 512) {
            int h = gcol >> 6, dh = gcol & 63;
            qo[(((size_t)b * H_ + h) * S_ + s) * DH_ + dh] = f2h(v + bias0[gcol]);
          } else {
            int n2 = gcol - 512;
            int two = n2 >> 9, h = (n2 >> 6) & 7, dh = n2 & 63;
            float vv = v + bias1[n2];
            if (two == 0) ko_[(((size_t)b * H_ + h) * S_ + s) * DH_ + dh] = f2h(vv);
            else          vto[(((size_t)b * H_ + h) * DH_ + dh) * S_ + s] = f2h(vv);
          }
        } else {
          // even gcol = a (l1), odd gcol = b (l2); pair lives in adjacent lanes
          float vp = __shfl_xor(v, 1);
          if ((l15 & 1) == 0) {
            float a = v, b = vp;
            float gv = a / (1.f + __expf(-a)) * b;
            outU[(size_t)grow * (N >> 1) + (gcol >> 1)] = f2bf(gv);
          }
        }
      }
    }
  }
}

// ---------------- 64x64 GEMM for small-N layers (512 blocks) ----------------
// EPI 2: +bias0 +auxF(fp32) -> outF ; EPI 4: +auxH(bf16) -> outF
template<int EPI>
__global__ __launch_bounds__(256) void gemm64(
    const u16* __restrict__ A, const u16* __restrict__ Bt,
    int M, int N, int K,
    const float* __restrict__ bias0, const float* __restrict__ auxF,
    const u16* __restrict__ auxH, float* __restrict__ outF)
{
  __shared__ u16 As[64 * 32];
  __shared__ u16 Bs[64 * 32];
  int tid = threadIdx.x;
  int gx = blockIdx.x, gy = blockIdx.y;
  int l = tid & 63, w = tid >> 6;
  int l15 = l & 15, quad = l >> 4;
  int wm = (w >> 1) * 32, wn = (w & 1) * 32;
  f32x4 acc[2][2] = {};

  const u16* Ag = A  + (size_t)(gy * 64 + (tid >> 2)) * K + (tid & 3) * 8;
  const u16* Bg = Bt + (size_t)(gx * 64 + (tid >> 2)) * K + (tid & 3) * 8;

  for (int ko = 0; ko < K; ko += 32) {
    __syncthreads();
    gl_lds16(Ag + ko, &As[tid * 8]);
    gl_lds16(Bg + ko, &Bs[tid * 8]);
    __syncthreads();
    sh8 af[2], bfr[2];
    #pragma unroll
    for (int mi = 0; mi < 2; mi++)
      af[mi] = *(const sh8*)&As[(wm + mi * 16 + l15) * 32 + quad * 8];
    #pragma unroll
    for (int ni = 0; ni < 2; ni++)
      bfr[ni] = *(const sh8*)&Bs[(wn + ni * 16 + l15) * 32 + quad * 8];
    #pragma unroll
    for (int mi = 0; mi < 2; mi++)
      #pragma unroll
      for (int ni = 0; ni < 2; ni++)
        acc[mi][ni] = __builtin_amdgcn_mfma_f32_16x16x32_bf16(af[mi], bfr[ni], acc[mi][ni], 0, 0, 0);
  }

  #pragma unroll
  for (int mi = 0; mi < 2; mi++) {
    #pragma unroll
    for (int ni = 0; ni < 2; ni++) {
      #pragma unroll
      for (int r = 0; r < 4; r++) {
        int grow = gy * 64 + wm + mi * 16 + quad * 4 + r;
        int gcol = gx * 64 + wn + ni * 16 + l15;
        float v = acc[mi][ni][r];
        if (EPI == 2) v += bias0[gcol] + auxF[(size_t)grow * N + gcol];
        else          v += bf2f(auxH[(size_t)grow * N + gcol]);
        outF[(size_t)grow * N + gcol] = v;
      }
    }
  }
}

// ---------------- sparse attention v4: e'=exp(s-8) f16 keys, padded LDS ----------------
#define RSTRIDE 1032   // halves; 2064 B = 16B-aligned, +8 pad breaks power-of-2 banks
__global__ __launch_bounds__(256, 4) void attn_kernel(
    const u16* __restrict__ q, const u16* __restrict__ kk,
    const u16* __restrict__ vt, u16* __restrict__ attn)
{
  __shared__ u16 scb[16 * RSTRIDE];   // 33 KB

  int tid = threadIdx.x;
  int l = tid & 63, w = tid >> 6;
  int l15 = l & 15, quad = l >> 4;
  int blk = blockIdx.x;
  int bh = blk >> 6;             // b*8+h
  int r0 = (blk & 63) << 4;      // query tile start

  const u16* qb = q  + ((size_t)bh * S_ + r0) * DH_;
  const u16* kb = kk + (size_t)bh * S_ * DH_;
  const u16* vb = vt + (size_t)bh * DH_ * S_;

  h8 aq0 = *(const h8*)(qb + l15 * DH_ + quad * 8);
  h8 aq1 = *(const h8*)(qb + l15 * DH_ + 32 + quad * 8);

  // ---- phase A: e' = exp(score - 8) -> LDS f16 (monotone non-negative keys)
  #pragma unroll
  for (int i = 0; i < 16; i++) {
    int t0 = ((i << 2) | w) << 4;
    const u16* kr = kb + (size_t)(t0 + l15) * DH_;
    h8 bk0 = *(const h8*)(kr + quad * 8);
    h8 bk1 = *(const h8*)(kr + 32 + quad * 8);
    f32x4 s4 = {};
    s4 = __builtin_amdgcn_mfma_f32_16x16x32_f16(bk0, aq0, s4, 0, 0, 0);
    s4 = __builtin_amdgcn_mfma_f32_16x16x32_f16(bk1, aq1, s4, 0, 0, 0);
    h4 hv;
    #pragma unroll
    for (int r = 0; r < 4; r++) hv[r] = (_Float16)__expf(s4[r] * 0.125f - 8.0f);
    // D[t][qrow]: qrow = l15, cols t0+quad*4..+3
    *(h4*)(scb + l15 * RSTRIDE + t0 + quad * 4) = hv;
  }
  __syncthreads();   // B1

  // ---- phase B: 64 e'-values per thread as 32 packed f16 words (bits = keys)
  int row = tid >> 4, l16 = tid & 15;
  u16* rowp = scb + row * RSTRIDE;
  uint32_t kv[32];
  #pragma unroll
  for (int u = 0; u < 16; u++) {
    uint2 rr = *(const uint2*)(rowp + 4 * l16 + 64 * u);
    kv[2 * u] = rr.x; kv[2 * u + 1] = rr.y;
  }
  // Z1 via packed f16 tree sum (values <= ~0.14, sum <= ~150: safe in f16)
  h2f zacc = __builtin_bit_cast(h2f, kv[0]);
  #pragma unroll
  for (int t = 1; t < 32; t++) zacc = zacc + __builtin_bit_cast(h2f, kv[t]);
  float Z1 = (float)zacc[0] + (float)zacc[1];
  #pragma unroll
  for (int d = 1; d < 16; d <<= 1) Z1 += __shfl_xor(Z1, d);
  float invZ = 1.0f / Z1;

  // bisect key threshold (f16 bits, sign=0): largest T with count >= ~512
  us2 onep; onep[0] = 1; onep[1] = 1;
  uint32_t lo = 0, Tf = 0;
  bool done = false;
  for (int bit = 14; bit >= 0; bit--) {
    uint32_t cand = lo | (1u << bit);
    uint32_t tm1 = cand - 1u;
    us2 tp; tp[0] = (unsigned short)tm1; tp[1] = (unsigned short)tm1;
    uint32_t acc = 0;
    #pragma unroll
    for (int t = 0; t < 32; t++) {
      us2 a = __builtin_bit_cast(us2, kv[t]);
      us2 d = __builtin_elementwise_sub_sat(a, tp);   // v_pk_sub_u16 clamp
      d = __builtin_elementwise_min(d, onep);         // v_pk_min_u16
      acc += __builtin_bit_cast(uint32_t, d);
    }
    uint32_t cnt = (acc & 0xFFFFu) + (acc >> 16);
    #pragma unroll
    for (int d2 = 1; d2 < 16; d2 <<= 1) cnt += __shfl_xor(cnt, d2);
    bool win = (cnt >= 480u && cnt <= 544u);
    if (win && !done) Tf = cand;
    done = done || win;
    if (cnt >= 512u) lo = cand;
    if (__all(done)) break;
  }
  uint32_t T = done ? Tf : lo;

  // pass 2: c = kept ? exp(e'*invZ) : 1 ; accumulate Z2; repack f16
  float Z2 = 0.f;
  #pragma unroll
  for (int t = 0; t < 32; t++) {
    uint32_t km = kv[t];
    float e0 = h_lo(km), e1 = h_hi(km);
    float c0 = ((km & 0xFFFFu) >= T) ? __expf(e0 * invZ) : 1.0f;
    float c1 = ((km >> 16)     >= T) ? __expf(e1 * invZ) : 1.0f;
    Z2 += c0 + c1;
    h2f cp; cp[0] = (_Float16)c0; cp[1] = (_Float16)c1;
    kv[t] = __builtin_bit_cast(uint32_t, cp);
  }
  #pragma unroll
  for (int d = 1; d < 16; d <<= 1) Z2 += __shfl_xor(Z2, d);
  _Float16 zh = (_Float16)(1.0f / Z2);
  h2f zp; zp[0] = zh; zp[1] = zh;

  // scale by 1/Z2 and store back to the same slots
  #pragma unroll
  for (int u = 0; u < 16; u++) {
    h2f a = __builtin_bit_cast(h2f, kv[2 * u]) * zp;
    h2f b = __builtin_bit_cast(h2f, kv[2 * u + 1]) * zp;
    uint2 ov;
    ov.x = __builtin_bit_cast(uint32_t, a);
    ov.y = __builtin_bit_cast(uint32_t, b);
    *(uint2*)(rowp + 4 * l16 + 64 * u) = ov;
  }
  __syncthreads();   // B2

  // ---- phase E: o = c' @ V via f16 MFMA (c' carries 1/Z2); b128 LDS reads
  int n0 = w << 4;
  const u16* crow = scb + l15 * RSTRIDE;
  f32x4 oacc = {};
  #pragma unroll
  for (int kt = 0; kt < 32; kt++) {
    h8 ca = *(const h8*)(crow + kt * 32 + quad * 8);
    h8 vv = *(const h8*)(vb + (size_t)(n0 + l15) * S_ + kt * 32 + quad * 8);
    oacc = __builtin_amdgcn_mfma_f32_16x16x32_f16(ca, vv, oacc, 0, 0, 0);
  }
  int b = bh >> 3, hh = bh & 7;
  #pragma unroll
  for (int r = 0; r < 4; r++) {
    int rr = quad * 4 + r;
    attn[((size_t)b * S_ + r0 + rr) * D_ + hh * DH_ + n0 + l15] = f2bf(oacc[r]);
  }
}

// ---------------- RMS norm over D per row: fp32 in, bf16 out ----------------
__global__ __launch_bounds__(128) void rms_kernel(const float* __restrict__ in,
                                                  const float* __restrict__ w,
                                                  u16* __restrict__ out) {
  int row = blockIdx.x;
  int tid = threadIdx.x;
  const float* r = in + (size_t)row * D_;
  float v0 = r[tid], v1 = r[tid + 128], v2 = r[tid + 256], v3 = r[tid + 384];
  float s = v0 * v0 + v1 * v1 + v2 * v2 + v3 * v3;
  #pragma unroll
  for (int d = 1; d < 64; d <<= 1) s += __shfl_xor(s, d);
  __shared__ float red[2];
  if ((tid & 63) == 0) red[tid >> 6] = s;
  __syncthreads();
  s = red[0] + red[1];
  float rs = rsqrtf(s * (1.0f / 512.0f) + 1e-6f);
  out[(size_t)row * D_ + tid      ] = f2bf(v0 * rs * w[tid      ]);
  out[(size_t)row * D_ + tid + 128] = f2bf(v1 * rs * w[tid + 128]);
  out[(size_t)row * D_ + tid + 256] = f2bf(v2 * rs * w[tid + 256]);
  out[(size_t)row * D_ + tid + 384] = f2bf(v3 * rs * w[tid + 384]);
}

// ---------------- instance norm: two-stage stats (512-block stage1) ----------------
__global__ __launch_bounds__(256) void inorm_stats1(const float* __restrict__ y,
                                                    float* __restrict__ part) {
  int b = blockIdx.x, dc = blockIdx.y, sc = blockIdx.z;
  int dl = threadIdx.x & 63, sl = threadIdx.x >> 6;
  int d = dc * 64 + dl;
  const float* yb = y + (size_t)b * S_ * D_ + (size_t)(sc * 64 + sl * 16) * D_ + d;
  float s1 = 0.f, s2 = 0.f;
  #pragma unroll
  for (int i = 0; i < 16; i++) {
    float v = yb[(size_t)i * D_];
    s1 += v; s2 += v * v;
  }
  __shared__ float r1[256], r2[256];
  r1[threadIdx.x] = s1; r2[threadIdx.x] = s2;
  __syncthreads();
  if (sl == 0) {
    s1 = r1[dl] + r1[dl + 64] + r1[dl + 128] + r1[dl + 192];
    s2 = r2[dl] + r2[dl + 64] + r2[dl + 128] + r2[dl + 192];
    float2 p; p.x = s1; p.y = s2;
    *(float2*)&part[(((size_t)(b * 8 + dc) * 64 + dl) * 16 + sc) * 2] = p;
  }
}

__global__ __launch_bounds__(256) void inorm_stats2(const float* __restrict__ part,
                                                    float* __restrict__ stats) {
  int idx = blockIdx.x * 256 + threadIdx.x;   // (b*512+d), 2048 total
  float s1 = 0.f, s2 = 0.f;
  #pragma unroll
  for (int i = 0; i < 16; i++) {
    float2 p = *(const float2*)&part[((size_t)idx * 16 + i) * 2];
    s1 += p.x; s2 += p.y;
  }
  float m = s1 * (1.f / 1024.f);
  float var = s2 * (1.f / 1024.f) - m * m;
  stats[idx * 2]     = m;
  stats[idx * 2 + 1] = rsqrtf(var + 1e-5f);
}

__global__ __launch_bounds__(256) void inorm_apply(const float* __restrict__ y,
                                                   const float* __restrict__ stats,
                                                   const float* __restrict__ w,
                                                   const float* __restrict__ bias,
                                                   float* __restrict__ out) {
  int row = blockIdx.x;
  int b = row >> 10;
  int tid = threadIdx.x;
  #pragma unroll
  for (int i = 0; i < 2; i++) {
    int d = tid + i * 256;
    float m  = stats[((size_t)b * D_ + d) * 2];
    float rs = stats[((size_t)b * D_ + d) * 2 + 1];
    float v = y[(size_t)row * D_ + d];
    out[(size_t)row * D_ + d] = (v - m) * rs * w[d] + bias[d];
  }
}

// ---------------- launch ----------------
extern "C" void kernel_launch(void* const* d_in, const int* in_sizes, int n_in,
                              void* d_out, int out_size, void* d_ws, size_t ws_size,
                              hipStream_t stream) {
  const float* x    = (const float*)d_in[0];
  const float* Wq   = (const float*)d_in[1];
  const float* bq   = (const float*)d_in[2];
  const float* Wkv  = (const float*)d_in[3];
  const float* bkv  = (const float*)d_in[4];
  const float* Wo   = (const float*)d_in[5];
  const float* bo   = (const float*)d_in[6];
  const float* rmsw = (const float*)d_in[7];
  const float* l1   = (const float*)d_in[8];
  const float* l2   = (const float*)d_in[9];
  const float* l3   = (const float*)d_in[10];
  const float* inw  = (const float*)d_in[11];
  const float* inb  = (const float*)d_in[12];
  float* out = (float*)d_out;

  char* ws = (char*)d_ws;
  size_t off = 0;
  auto alloc = [&](size_t n) { char* p = ws + off; off += (n + 255) & ~(size_t)255; return p; };
  u16*  xb   = (u16*) alloc((size_t)M_ * D_ * 2);
  u16*  Wt1  = (u16*) alloc((size_t)1536 * 512 * 2);
  u16*  Wot  = (u16*) alloc((size_t)512 * 512 * 2);
  u16*  W12t = (u16*) alloc((size_t)3072 * 512 * 2);   // interleaved l1/l2
  u16*  l3t  = (u16*) alloc((size_t)512 * 1536 * 2);
  u16*  qb   = (u16*) alloc((size_t)M_ * D_ * 2);      // f16 [B,H,S,DH]
  u16*  kb   = (u16*) alloc((size_t)M_ * D_ * 2);      // f16 [B,H,S,DH]
  u16*  vtb  = (u16*) alloc((size_t)M_ * D_ * 2);      // f16 [B,H,DH,S]
  u16*  attn = (u16*) alloc((size_t)M_ * D_ * 2);      // bf16 [B,S,D]
  float* tmpF = (float*)alloc((size_t)M_ * D_ * 4);
  u16*  hhat = (u16*) alloc((size_t)M_ * D_ * 2);
  u16*  g    = (u16*) alloc((size_t)M_ * INNER_ * 2);
  float* part  = (float*)alloc((size_t)B_ * D_ * 16 * 2 * 4);
  float* stats = (float*)alloc((size_t)B_ * D_ * 2 * 4);

  transpose_all<<<832, 256, 0, stream>>>(Wq, Wkv, Wo, l1, l2, l3, Wt1, Wot, W12t, l3t);
  f2b_kernel<<<2048, 256, 0, stream>>>(x, xb);

  gemm_bt<1><<<dim3(12, 32), 256, 0, stream>>>(xb, Wt1, M_, 1536, 512,
      bq, bkv, nullptr, qb, kb, vtb);

  attn_kernel<<<2048, 256, 0, stream>>>(qb, kb, vtb, attn);

  gemm64<2><<<dim3(8, 64), 256, 0, stream>>>(attn, Wot, M_, 512, 512,
      bo, x, nullptr, tmpF);

  rms_kernel<<<4096, 128, 0, stream>>>(tmpF, rmsw, hhat);

  // FFN up + silu fused: writes g [M, 1536] directly
  gemm_bt<3><<<dim3(24, 32), 256, 0, stream>>>(hhat, W12t, M_, 3072, 512,
      nullptr, nullptr, g, nullptr, nullptr, nullptr);

  gemm64<4><<<dim3(8, 64), 256, 0, stream>>>(g, l3t, M_, 512, 1536,
      nullptr, nullptr, hhat, tmpF);

  inorm_stats1<<<dim3(4, 8, 16), 256, 0, stream>>>(tmpF, part);
  inorm_stats2<<<8, 256, 0, stream>>>(part, stats);
  inorm_apply<<<4096, 256, 0, stream>>>(tmpF, stats, inw, inb, out);
}

// Round 8
// 257.265 us; speedup vs baseline: 1.2161x; 1.0317x over previous
//
#include <hip/hip_runtime.h>
#include <stdint.h>

#define B_ 4
#define S_ 1024
#define D_ 512
#define H_ 8
#define DH_ 64
#define INNER_ 1536
#define M_ (B_*S_)   // 4096

typedef unsigned short u16;
typedef __attribute__((ext_vector_type(8))) short sh8;      // 8 bf16
typedef __attribute__((ext_vector_type(8))) _Float16 h8;    // 8 f16
typedef __attribute__((ext_vector_type(4))) _Float16 h4;    // 4 f16
typedef __attribute__((ext_vector_type(2))) _Float16 h2f;   // 2 f16
typedef __attribute__((ext_vector_type(4))) float f32x4;

typedef __attribute__((address_space(1))) const void cgv;
typedef __attribute__((address_space(3))) void lv;
__device__ __forceinline__ void gl_lds16(const void* g, void* l) {
  __builtin_amdgcn_global_load_lds((cgv*)g, (lv*)l, 16, 0, 0);
}

__device__ __forceinline__ float bf2f(u16 u) {
  union { unsigned int i; float f; } v; v.i = ((unsigned int)u) << 16; return v.f;
}
__device__ __forceinline__ u16 f2bf(float f) {
  union { float f; unsigned int i; } v; v.f = f;
  unsigned int u = v.i;
  return (u16)((u + 0x7FFFu + ((u >> 16) & 1u)) >> 16);
}
__device__ __forceinline__ u16 f2h(float f) {
  _Float16 h = (_Float16)f;
  return *(u16*)&h;
}

// ---------------- fp32 -> bf16 convert ----------------
__global__ __launch_bounds__(256) void f2b_kernel(const float* __restrict__ in,
                                                  u16* __restrict__ out) {
  int i = (blockIdx.x * 256 + threadIdx.x) * 4;
  float4 v = *(const float4*)(in + i);
  uint2 o;
  o.x = (unsigned int)f2bf(v.x) | ((unsigned int)f2bf(v.y) << 16);
  o.y = (unsigned int)f2bf(v.z) | ((unsigned int)f2bf(v.w) << 16);
  *(uint2*)(out + i) = o;
}

// ---------------- all weight transposes in one launch ----------------
// l1/l2 interleaved into W12t: l1 col j -> row 2j, l2 col j -> row 2j+1.
__global__ __launch_bounds__(256) void transpose_all(
    const float* __restrict__ Wq, const float* __restrict__ Wkv,
    const float* __restrict__ Wo, const float* __restrict__ l1,
    const float* __restrict__ l2, const float* __restrict__ l3,
    u16* __restrict__ Wt1, u16* __restrict__ Wot,
    u16* __restrict__ W12t, u16* __restrict__ l3t)
{
  int i = blockIdx.x;
  const float* in; u16* outp; int K, N, bx, by, rs = 1, ra = 0;
  if (i < 64)       { in = Wq;  outp = Wt1;              K = 512;  N = 512;           bx = i & 7;  by = i >> 3; }
  else if (i < 192) { in = Wkv; outp = Wt1 + 512 * 512;  K = 512;  N = 1024; i -= 64; bx = i & 15; by = i >> 4; }
  else if (i < 256) { in = Wo;  outp = Wot;              K = 512;  N = 512;  i -= 192; bx = i & 7;  by = i >> 3; }
  else if (i < 448) { in = l1;  outp = W12t;             K = 512;  N = 1536; i -= 256; bx = i % 24; by = i / 24; rs = 2; ra = 0; }
  else if (i < 640) { in = l2;  outp = W12t;             K = 512;  N = 1536; i -= 448; bx = i % 24; by = i / 24; rs = 2; ra = 1; }
  else              { in = l3;  outp = l3t;              K = 1536; N = 512;  i -= 640; bx = i & 7;  by = i >> 3; }

  __shared__ u16 tile[64][65];
  int tx = threadIdx.x & 63, ty = threadIdx.x >> 6;
  int n0 = bx * 64, k0 = by * 64;
  #pragma unroll
  for (int t = 0; t < 16; t++) {
    int k = ty + t * 4;
    tile[k][tx] = f2bf(in[(size_t)(k0 + k) * N + n0 + tx]);
  }
  __syncthreads();
  #pragma unroll
  for (int t = 0; t < 16; t++) {
    int n = ty + t * 4;
    outp[(size_t)((n0 + n) * rs + ra) * K + k0 + tx] = tile[tx][n];
  }
}

// ---------------- 128x128 GEMM, glds staging ----------------
// EPI 1: qkv scatter (+biases), q/k/v stored f16
// EPI 3: silu-fused FFN-up: interleaved l1/l2 cols; writes g[M, N/2] bf16
template<int EPI>
__global__ __launch_bounds__(256) void gemm_bt(
    const u16* __restrict__ A, const u16* __restrict__ Bt,
    int M, int N, int K,
    const float* __restrict__ bias0, const float* __restrict__ bias1,
    u16* __restrict__ outU,
    u16* __restrict__ qo, u16* __restrict__ ko_, u16* __restrict__ vto)
{
  __shared__ u16 As[128 * 32];
  __shared__ u16 Bs[128 * 32];
  int tid = threadIdx.x;
  int gx = blockIdx.x, gy = blockIdx.y;
  int l = tid & 63, w = tid >> 6;
  int l15 = l & 15, quad = l >> 4;
  int wm = (w >> 1) * 64, wn = (w & 1) * 64;
  f32x4 acc[4][4] = {};

  const u16* Ag = A  + (size_t)(gy * 128 + (tid >> 2)) * K + (tid & 3) * 8;
  const u16* Bg = Bt + (size_t)(gx * 128 + (tid >> 2)) * K + (tid & 3) * 8;

  for (int ko = 0; ko < K; ko += 32) {
    __syncthreads();
    gl_lds16(Ag + ko,                  &As[tid * 8]);
    gl_lds16(Ag + (size_t)64 * K + ko, &As[2048 + tid * 8]);
    gl_lds16(Bg + ko,                  &Bs[tid * 8]);
    gl_lds16(Bg + (size_t)64 * K + ko, &Bs[2048 + tid * 8]);
    __syncthreads();
    sh8 af[4], bfr[4];
    #pragma unroll
    for (int mi = 0; mi < 4; mi++)
      af[mi] = *(const sh8*)&As[(wm + mi * 16 + l15) * 32 + quad * 8];
    #pragma unroll
    for (int ni = 0; ni < 4; ni++)
      bfr[ni] = *(const sh8*)&Bs[(wn + ni * 16 + l15) * 32 + quad * 8];
    #pragma unroll
    for (int mi = 0; mi < 4; mi++)
      #pragma unroll
      for (int ni = 0; ni < 4; ni++)
        acc[mi][ni] = __builtin_amdgcn_mfma_f32_16x16x32_bf16(af[mi], bfr[ni], acc[mi][ni], 0, 0, 0);
  }

  #pragma unroll
  for (int mi = 0; mi < 4; mi++) {
    #pragma unroll
    for (int ni = 0; ni < 4; ni++) {
      #pragma unroll
      for (int r = 0; r < 4; r++) {
        int grow = gy * 128 + wm + mi * 16 + quad * 4 + r;
        int gcol = gx * 128 + wn + ni * 16 + l15;
        float v = acc[mi][ni][r];
        if (EPI == 1) {
          int b = grow >> 10, s = grow & 1023;
          if (gcol < 512) {
            int h = gcol >> 6, dh = gcol & 63;
            qo[(((size_t)b * H_ + h) * S_ + s) * DH_ + dh] = f2h(v + bias0[gcol]);
          } else {
            int n2 = gcol - 512;
            int two = n2 >> 9, h = (n2 >> 6) & 7, dh = n2 & 63;
            float vv = v + bias1[n2];
            if (two == 0) ko_[(((size_t)b * H_ + h) * S_ + s) * DH_ + dh] = f2h(vv);
            else          vto[(((size_t)b * H_ + h) * DH_ + dh) * S_ + s] = f2h(vv);
          }
        } else {
          // even gcol = a (l1), odd gcol = b (l2); pair lives in adjacent lanes
          float vp = __shfl_xor(v, 1);
          if ((l15 & 1) == 0) {
            float a = v, b = vp;
            float gv = a / (1.f + __expf(-a)) * b;
            outU[(size_t)grow * (N >> 1) + (gcol >> 1)] = f2bf(gv);
          }
        }
      }
    }
  }
}

// ---------------- 64x64 GEMM for small-N layers (512 blocks) ----------------
// EPI 2: +bias0 +auxF(fp32) -> outF ; EPI 4: +auxH(bf16) -> outF
template<int EPI>
__global__ __launch_bounds__(256) void gemm64(
    const u16* __restrict__ A, const u16* __restrict__ Bt,
    int M, int N, int K,
    const float* __restrict__ bias0, const float* __restrict__ auxF,
    const u16* __restrict__ auxH, float* __restrict__ outF)
{
  __shared__ u16 As[64 * 32];
  __shared__ u16 Bs[64 * 32];
  int tid = threadIdx.x;
  int gx = blockIdx.x, gy = blockIdx.y;
  int l = tid & 63, w = tid >> 6;
  int l15 = l & 15, quad = l >> 4;
  int wm = (w >> 1) * 32, wn = (w & 1) * 32;
  f32x4 acc[2][2] = {};

  const u16* Ag = A  + (size_t)(gy * 64 + (tid >> 2)) * K + (tid & 3) * 8;
  const u16* Bg = Bt + (size_t)(gx * 64 + (tid >> 2)) * K + (tid & 3) * 8;

  for (int ko = 0; ko < K; ko += 32) {
    __syncthreads();
    gl_lds16(Ag + ko, &As[tid * 8]);
    gl_lds16(Bg + ko, &Bs[tid * 8]);
    __syncthreads();
    sh8 af[2], bfr[2];
    #pragma unroll
    for (int mi = 0; mi < 2; mi++)
      af[mi] = *(const sh8*)&As[(wm + mi * 16 + l15) * 32 + quad * 8];
    #pragma unroll
    for (int ni = 0; ni < 2; ni++)
      bfr[ni] = *(const sh8*)&Bs[(wn + ni * 16 + l15) * 32 + quad * 8];
    #pragma unroll
    for (int mi = 0; mi < 2; mi++)
      #pragma unroll
      for (int ni = 0; ni < 2; ni++)
        acc[mi][ni] = __builtin_amdgcn_mfma_f32_16x16x32_bf16(af[mi], bfr[ni], acc[mi][ni], 0, 0, 0);
  }

  #pragma unroll
  for (int mi = 0; mi < 2; mi++) {
    #pragma unroll
    for (int ni = 0; ni < 2; ni++) {
      #pragma unroll
      for (int r = 0; r < 4; r++) {
        int grow = gy * 64 + wm + mi * 16 + quad * 4 + r;
        int gcol = gx * 64 + wn + ni * 16 + l15;
        float v = acc[mi][ni][r];
        if (EPI == 2) v += bias0[gcol] + auxF[(size_t)grow * N + gcol];
        else          v += bf2f(auxH[(size_t)grow * N + gcol]);
        outF[(size_t)grow * N + gcol] = v;
      }
    }
  }
}

// ---------------- sparse attention v5: maskless Taylor softmax2 ----------------
// Top-512 mask removed: bottom-half weights satisfy sum(w_bot) <= 0.5 (softmax sums
// to 1), so unmasked softmax2 differs by dZ2/Z2 <= 4.9e-4 and ~1e-5 rms numerator
// noise -> <=1e-3 end-to-end, vs 0.099 tolerance. exp(w), w<=~0.13, via 3-term
// Horner in packed f16 (err w^4/24 <= 1e-5). Z2 = 1024 + sum(c-1) is exact.
#define RSTRIDE 1032   // halves; 2064 B row stride, 16B-aligned
__global__ __launch_bounds__(256, 4) void attn_kernel(
    const u16* __restrict__ q, const u16* __restrict__ kk,
    const u16* __restrict__ vt, u16* __restrict__ attn)
{
  __shared__ u16 scb[16 * RSTRIDE];   // 33 KB

  int tid = threadIdx.x;
  int l = tid & 63, w = tid >> 6;
  int l15 = l & 15, quad = l >> 4;
  int blk = blockIdx.x;
  // XCD-aware swizzle: 4 bh per XCD (1 MB K/V working set per XCD L2)
  int xcd = blk & 7, li = blk >> 3;
  int bh = xcd * 4 + (li & 3);
  int r0 = (li >> 2) << 4;

  const u16* qb = q  + ((size_t)bh * S_ + r0) * DH_;
  const u16* kb = kk + (size_t)bh * S_ * DH_;
  const u16* vb = vt + (size_t)bh * DH_ * S_;

  h8 aq0 = *(const h8*)(qb + l15 * DH_ + quad * 8);
  h8 aq1 = *(const h8*)(qb + l15 * DH_ + 32 + quad * 8);

  // ---- phase A: e' = exp(score/8 - 8) -> LDS f16
  #pragma unroll
  for (int i = 0; i < 16; i++) {
    int t0 = ((i << 2) | w) << 4;
    const u16* kr = kb + (size_t)(t0 + l15) * DH_;
    h8 bk0 = *(const h8*)(kr + quad * 8);
    h8 bk1 = *(const h8*)(kr + 32 + quad * 8);
    f32x4 s4 = {};
    s4 = __builtin_amdgcn_mfma_f32_16x16x32_f16(bk0, aq0, s4, 0, 0, 0);
    s4 = __builtin_amdgcn_mfma_f32_16x16x32_f16(bk1, aq1, s4, 0, 0, 0);
    h4 hv;
    #pragma unroll
    for (int r = 0; r < 4; r++)
      hv[r] = (_Float16)exp2f(fmaf(s4[r], 0.18033688f, -11.5415603f));  // exp(s/8-8)
    *(h4*)(scb + l15 * RSTRIDE + t0 + quad * 4) = hv;
  }
  __syncthreads();   // B1

  // ---- phase B: Z1, then c' = exp(w)/Z2 via packed-f16 Horner (no exp, no top-k)
  int row = tid >> 4, l16 = tid & 15;
  u16* rowp = scb + row * RSTRIDE;
  uint32_t kv[32];
  h2f z1a = (h2f)(_Float16)0;
  #pragma unroll
  for (int u = 0; u < 16; u++) {
    uint2 rr = *(const uint2*)(rowp + 4 * l16 + 64 * u);
    kv[2 * u] = rr.x; kv[2 * u + 1] = rr.y;
    z1a = z1a + __builtin_bit_cast(h2f, rr.x);
    z1a = z1a + __builtin_bit_cast(h2f, rr.y);
  }
  float Z1 = (float)z1a[0] + (float)z1a[1];
  #pragma unroll
  for (int d = 1; d < 16; d <<= 1) Z1 += __shfl_xor(Z1, d);
  _Float16 izh = (_Float16)(1.0f / Z1);
  h2f izv; izv[0] = izh; izv[1] = izh;
  h2f onev; onev[0] = (_Float16)1.f; onev[1] = (_Float16)1.f;
  h2f c2v;  c2v[0] = (_Float16)0.5f; c2v[1] = (_Float16)0.5f;
  h2f c6v;  c6v[0] = (_Float16)(1.f/6.f); c6v[1] = (_Float16)(1.f/6.f);

  // cm1 = exp(w)-1 ~= w*(1 + w*(1/2 + w/6)); accumulate in packed f16
  h2f sacc = (h2f)(_Float16)0;
  h2f cm1s[32];
  #pragma unroll
  for (int t = 0; t < 32; t++) {
    h2f e = __builtin_bit_cast(h2f, kv[t]);
    h2f wv = e * izv;
    h2f p = wv * c6v + c2v;
    h2f qq = wv * p + onev;
    h2f cm1 = wv * qq;
    sacc = sacc + cm1;
    cm1s[t] = cm1;
  }
  float s2 = (float)sacc[0] + (float)sacc[1];
  #pragma unroll
  for (int d = 1; d < 16; d <<= 1) s2 += __shfl_xor(s2, d);
  float Z2 = 1024.0f + s2;
  _Float16 zh = (_Float16)(1.0f / Z2);
  h2f zv; zv[0] = zh; zv[1] = zh;

  // c' = (1 + cm1)/Z2, store back
  #pragma unroll
  for (int u = 0; u < 16; u++) {
    h2f a = cm1s[2 * u] * zv + zv;
    h2f b = cm1s[2 * u + 1] * zv + zv;
    uint2 ov;
    ov.x = __builtin_bit_cast(uint32_t, a);
    ov.y = __builtin_bit_cast(uint32_t, b);
    *(uint2*)(rowp + 4 * l16 + 64 * u) = ov;
  }
  __syncthreads();   // B2

  // ---- phase E: o = c' @ V via f16 MFMA; b128 LDS reads
  int n0 = w << 4;
  const u16* crow = scb + l15 * RSTRIDE;
  f32x4 oacc = {};
  #pragma unroll
  for (int kt = 0; kt < 32; kt++) {
    h8 ca = *(const h8*)(crow + kt * 32 + quad * 8);
    h8 vv = *(const h8*)(vb + (size_t)(n0 + l15) * S_ + kt * 32 + quad * 8);
    oacc = __builtin_amdgcn_mfma_f32_16x16x32_f16(ca, vv, oacc, 0, 0, 0);
  }
  int b = bh >> 3, hh = bh & 7;
  #pragma unroll
  for (int r = 0; r < 4; r++) {
    int rr = quad * 4 + r;
    attn[((size_t)b * S_ + r0 + rr) * D_ + hh * DH_ + n0 + l15] = f2bf(oacc[r]);
  }
}

// ---------------- RMS norm over D per row: fp32 in, bf16 out ----------------
__global__ __launch_bounds__(128) void rms_kernel(const float* __restrict__ in,
                                                  const float* __restrict__ w,
                                                  u16* __restrict__ out) {
  int row = blockIdx.x;
  int tid = threadIdx.x;
  const float* r = in + (size_t)row * D_;
  float v0 = r[tid], v1 = r[tid + 128], v2 = r[tid + 256], v3 = r[tid + 384];
  float s = v0 * v0 + v1 * v1 + v2 * v2 + v3 * v3;
  #pragma unroll
  for (int d = 1; d < 64; d <<= 1) s += __shfl_xor(s, d);
  __shared__ float red[2];
  if ((tid & 63) == 0) red[tid >> 6] = s;
  __syncthreads();
  s = red[0] + red[1];
  float rs = rsqrtf(s * (1.0f / 512.0f) + 1e-6f);
  out[(size_t)row * D_ + tid      ] = f2bf(v0 * rs * w[tid      ]);
  out[(size_t)row * D_ + tid + 128] = f2bf(v1 * rs * w[tid + 128]);
  out[(size_t)row * D_ + tid + 256] = f2bf(v2 * rs * w[tid + 256]);
  out[(size_t)row * D_ + tid + 384] = f2bf(v3 * rs * w[tid + 384]);
}

// ---------------- instance norm: two-stage stats ----------------
__global__ __launch_bounds__(256) void inorm_stats1(const float* __restrict__ y,
                                                    float* __restrict__ part) {
  int b = blockIdx.x, dc = blockIdx.y, sc = blockIdx.z;
  int dl = threadIdx.x & 63, sl = threadIdx.x >> 6;
  int d = dc * 64 + dl;
  const float* yb = y + (size_t)b * S_ * D_ + (size_t)(sc * 64 + sl * 16) * D_ + d;
  float s1 = 0.f, s2 = 0.f;
  #pragma unroll
  for (int i = 0; i < 16; i++) {
    float v = yb[(size_t)i * D_];
    s1 += v; s2 += v * v;
  }
  __shared__ float r1[256], r2[256];
  r1[threadIdx.x] = s1; r2[threadIdx.x] = s2;
  __syncthreads();
  if (sl == 0) {
    s1 = r1[dl] + r1[dl + 64] + r1[dl + 128] + r1[dl + 192];
    s2 = r2[dl] + r2[dl + 64] + r2[dl + 128] + r2[dl + 192];
    float2 p; p.x = s1; p.y = s2;
    *(float2*)&part[(((size_t)(b * 8 + dc) * 64 + dl) * 16 + sc) * 2] = p;
  }
}

__global__ __launch_bounds__(256) void inorm_stats2(const float* __restrict__ part,
                                                    float* __restrict__ stats) {
  int idx = blockIdx.x * 256 + threadIdx.x;   // (b*512+d), 2048 total
  float s1 = 0.f, s2 = 0.f;
  #pragma unroll
  for (int i = 0; i < 16; i++) {
    float2 p = *(const float2*)&part[((size_t)idx * 16 + i) * 2];
    s1 += p.x; s2 += p.y;
  }
  float m = s1 * (1.f / 1024.f);
  float var = s2 * (1.f / 1024.f) - m * m;
  stats[idx * 2]     = m;
  stats[idx * 2 + 1] = rsqrtf(var + 1e-5f);
}

__global__ __launch_bounds__(256) void inorm_apply(const float* __restrict__ y,
                                                   const float* __restrict__ stats,
                                                   const float* __restrict__ w,
                                                   const float* __restrict__ bias,
                                                   float* __restrict__ out) {
  int row = blockIdx.x;
  int b = row >> 10;
  int tid = threadIdx.x;
  #pragma unroll
  for (int i = 0; i < 2; i++) {
    int d = tid + i * 256;
    float m  = stats[((size_t)b * D_ + d) * 2];
    float rs = stats[((size_t)b * D_ + d) * 2 + 1];
    float v = y[(size_t)row * D_ + d];
    out[(size_t)row * D_ + d] = (v - m) * rs * w[d] + bias[d];
  }
}

// ---------------- launch ----------------
extern "C" void kernel_launch(void* const* d_in, const int* in_sizes, int n_in,
                              void* d_out, int out_size, void* d_ws, size_t ws_size,
                              hipStream_t stream) {
  const float* x    = (const float*)d_in[0];
  const float* Wq   = (const float*)d_in[1];
  const float* bq   = (const float*)d_in[2];
  const float* Wkv  = (const float*)d_in[3];
  const float* bkv  = (const float*)d_in[4];
  const float* Wo   = (const float*)d_in[5];
  const float* bo   = (const float*)d_in[6];
  const float* rmsw = (const float*)d_in[7];
  const float* l1   = (const float*)d_in[8];
  const float* l2   = (const float*)d_in[9];
  const float* l3   = (const float*)d_in[10];
  const float* inw  = (const float*)d_in[11];
  const float* inb  = (const float*)d_in[12];
  float* out = (float*)d_out;

  char* ws = (char*)d_ws;
  size_t off = 0;
  auto alloc = [&](size_t n) { char* p = ws + off; off += (n + 255) & ~(size_t)255; return p; };
  u16*  xb   = (u16*) alloc((size_t)M_ * D_ * 2);
  u16*  Wt1  = (u16*) alloc((size_t)1536 * 512 * 2);
  u16*  Wot  = (u16*) alloc((size_t)512 * 512 * 2);
  u16*  W12t = (u16*) alloc((size_t)3072 * 512 * 2);   // interleaved l1/l2
  u16*  l3t  = (u16*) alloc((size_t)512 * 1536 * 2);
  u16*  qb   = (u16*) alloc((size_t)M_ * D_ * 2);      // f16 [B,H,S,DH]
  u16*  kb   = (u16*) alloc((size_t)M_ * D_ * 2);      // f16 [B,H,S,DH]
  u16*  vtb  = (u16*) alloc((size_t)M_ * D_ * 2);      // f16 [B,H,DH,S]
  u16*  attn = (u16*) alloc((size_t)M_ * D_ * 2);      // bf16 [B,S,D]
  float* tmpF = (float*)alloc((size_t)M_ * D_ * 4);
  u16*  hhat = (u16*) alloc((size_t)M_ * D_ * 2);
  u16*  g    = (u16*) alloc((size_t)M_ * INNER_ * 2);
  float* part  = (float*)alloc((size_t)B_ * D_ * 16 * 2 * 4);
  float* stats = (float*)alloc((size_t)B_ * D_ * 2 * 4);

  transpose_all<<<832, 256, 0, stream>>>(Wq, Wkv, Wo, l1, l2, l3, Wt1, Wot, W12t, l3t);
  f2b_kernel<<<2048, 256, 0, stream>>>(x, xb);

  gemm_bt<1><<<dim3(12, 32), 256, 0, stream>>>(xb, Wt1, M_, 1536, 512,
      bq, bkv, nullptr, qb, kb, vtb);

  attn_kernel<<<2048, 256, 0, stream>>>(qb, kb, vtb, attn);

  gemm64<2><<<dim3(8, 64), 256, 0, stream>>>(attn, Wot, M_, 512, 512,
      bo, x, nullptr, tmpF);

  rms_kernel<<<4096, 128, 0, stream>>>(tmpF, rmsw, hhat);

  // FFN up + silu fused: writes g [M, 1536] directly
  gemm_bt<3><<<dim3(24, 32), 256, 0, stream>>>(hhat, W12t, M_, 3072, 512,
      nullptr, nullptr, g, nullptr, nullptr, nullptr);

  gemm64<4><<<dim3(8, 64), 256, 0, stream>>>(g, l3t, M_, 512, 1536,
      nullptr, nullptr, hhat, tmpF);

  inorm_stats1<<<dim3(4, 8, 16), 256, 0, stream>>>(tmpF, part);
  inorm_stats2<<<8, 256, 0, stream>>>(part, stats);
  inorm_apply<<<4096, 256, 0, stream>>>(tmpF, stats, inw, inb, out);
}

// Round 9
// 236.462 us; speedup vs baseline: 1.3230x; 1.0880x over previous
//
#include <hip/hip_runtime.h>
#include <stdint.h>

#define B_ 4
#define S_ 1024
#define D_ 512
#define H_ 8
#define DH_ 64
#define INNER_ 1536
#define M_ (B_*S_)   // 4096

typedef unsigned short u16;
typedef __attribute__((ext_vector_type(8))) short sh8;      // 8 bf16
typedef __attribute__((ext_vector_type(8))) _Float16 h8;    // 8 f16
typedef __attribute__((ext_vector_type(4))) _Float16 h4;    // 4 f16
typedef __attribute__((ext_vector_type(2))) _Float16 h2f;   // 2 f16
typedef __attribute__((ext_vector_type(4))) float f32x4;

typedef __attribute__((address_space(1))) const void cgv;
typedef __attribute__((address_space(3))) void lv;
__device__ __forceinline__ void gl_lds16(const void* g, void* l) {
  __builtin_amdgcn_global_load_lds((cgv*)g, (lv*)l, 16, 0, 0);
}
// wait until <=N vm ops outstanding; ignore lgkm(15)/exp(7)
#define WAITVM(N) __builtin_amdgcn_s_waitcnt(0x0F70 | (N))

__device__ __forceinline__ float bf2f(u16 u) {
  union { unsigned int i; float f; } v; v.i = ((unsigned int)u) << 16; return v.f;
}
__device__ __forceinline__ u16 f2bf(float f) {
  union { float f; unsigned int i; } v; v.f = f;
  unsigned int u = v.i;
  return (u16)((u + 0x7FFFu + ((u >> 16) & 1u)) >> 16);
}
__device__ __forceinline__ u16 f2h(float f) {
  _Float16 h = (_Float16)f;
  return *(u16*)&h;
}

// ---------------- fp32 -> bf16 convert ----------------
__global__ __launch_bounds__(256) void f2b_kernel(const float* __restrict__ in,
                                                  u16* __restrict__ out) {
  int i = (blockIdx.x * 256 + threadIdx.x) * 4;
  float4 v = *(const float4*)(in + i);
  uint2 o;
  o.x = (unsigned int)f2bf(v.x) | ((unsigned int)f2bf(v.y) << 16);
  o.y = (unsigned int)f2bf(v.z) | ((unsigned int)f2bf(v.w) << 16);
  *(uint2*)(out + i) = o;
}

// ---------------- all weight transposes in one launch ----------------
// l1/l2 interleaved into W12t: l1 col j -> row 2j, l2 col j -> row 2j+1.
__global__ __launch_bounds__(256) void transpose_all(
    const float* __restrict__ Wq, const float* __restrict__ Wkv,
    const float* __restrict__ Wo, const float* __restrict__ l1,
    const float* __restrict__ l2, const float* __restrict__ l3,
    u16* __restrict__ Wt1, u16* __restrict__ Wot,
    u16* __restrict__ W12t, u16* __restrict__ l3t)
{
  int i = blockIdx.x;
  const float* in; u16* outp; int K, N, bx, by, rs = 1, ra = 0;
  if (i < 64)       { in = Wq;  outp = Wt1;              K = 512;  N = 512;           bx = i & 7;  by = i >> 3; }
  else if (i < 192) { in = Wkv; outp = Wt1 + 512 * 512;  K = 512;  N = 1024; i -= 64; bx = i & 15; by = i >> 4; }
  else if (i < 256) { in = Wo;  outp = Wot;              K = 512;  N = 512;  i -= 192; bx = i & 7;  by = i >> 3; }
  else if (i < 448) { in = l1;  outp = W12t;             K = 512;  N = 1536; i -= 256; bx = i % 24; by = i / 24; rs = 2; ra = 0; }
  else if (i < 640) { in = l2;  outp = W12t;             K = 512;  N = 1536; i -= 448; bx = i % 24; by = i / 24; rs = 2; ra = 1; }
  else              { in = l3;  outp = l3t;              K = 1536; N = 512;  i -= 640; bx = i & 7;  by = i >> 3; }

  __shared__ u16 tile[64][65];
  int tx = threadIdx.x & 63, ty = threadIdx.x >> 6;
  int n0 = bx * 64, k0 = by * 64;
  #pragma unroll
  for (int t = 0; t < 16; t++) {
    int k = ty + t * 4;
    tile[k][tx] = f2bf(in[(size_t)(k0 + k) * N + n0 + tx]);
  }
  __syncthreads();
  #pragma unroll
  for (int t = 0; t < 16; t++) {
    int n = ty + t * 4;
    outp[(size_t)((n0 + n) * rs + ra) * K + k0 + tx] = tile[tx][n];
  }
}

// ---------------- 128x128 GEMM, glds staging ----------------
// EPI 1: qkv scatter (+biases), q/k/v stored f16
// EPI 3: silu-fused FFN-up: interleaved l1/l2 cols; writes g[M, N/2] bf16
template<int EPI>
__global__ __launch_bounds__(256) void gemm_bt(
    const u16* __restrict__ A, const u16* __restrict__ Bt,
    int M, int N, int K,
    const float* __restrict__ bias0, const float* __restrict__ bias1,
    u16* __restrict__ outU,
    u16* __restrict__ qo, u16* __restrict__ ko_, u16* __restrict__ vto)
{
  __shared__ u16 As[128 * 32];
  __shared__ u16 Bs[128 * 32];
  int tid = threadIdx.x;
  int gx = blockIdx.x, gy = blockIdx.y;
  int l = tid & 63, w = tid >> 6;
  int l15 = l & 15, quad = l >> 4;
  int wm = (w >> 1) * 64, wn = (w & 1) * 64;
  f32x4 acc[4][4] = {};

  const u16* Ag = A  + (size_t)(gy * 128 + (tid >> 2)) * K + (tid & 3) * 8;
  const u16* Bg = Bt + (size_t)(gx * 128 + (tid >> 2)) * K + (tid & 3) * 8;

  for (int ko = 0; ko < K; ko += 32) {
    __syncthreads();
    gl_lds16(Ag + ko,                  &As[tid * 8]);
    gl_lds16(Ag + (size_t)64 * K + ko, &As[2048 + tid * 8]);
    gl_lds16(Bg + ko,                  &Bs[tid * 8]);
    gl_lds16(Bg + (size_t)64 * K + ko, &Bs[2048 + tid * 8]);
    __syncthreads();
    sh8 af[4], bfr[4];
    #pragma unroll
    for (int mi = 0; mi < 4; mi++)
      af[mi] = *(const sh8*)&As[(wm + mi * 16 + l15) * 32 + quad * 8];
    #pragma unroll
    for (int ni = 0; ni < 4; ni++)
      bfr[ni] = *(const sh8*)&Bs[(wn + ni * 16 + l15) * 32 + quad * 8];
    #pragma unroll
    for (int mi = 0; mi < 4; mi++)
      #pragma unroll
      for (int ni = 0; ni < 4; ni++)
        acc[mi][ni] = __builtin_amdgcn_mfma_f32_16x16x32_bf16(af[mi], bfr[ni], acc[mi][ni], 0, 0, 0);
  }

  #pragma unroll
  for (int mi = 0; mi < 4; mi++) {
    #pragma unroll
    for (int ni = 0; ni < 4; ni++) {
      #pragma unroll
      for (int r = 0; r < 4; r++) {
        int grow = gy * 128 + wm + mi * 16 + quad * 4 + r;
        int gcol = gx * 128 + wn + ni * 16 + l15;
        float v = acc[mi][ni][r];
        if (EPI == 1) {
          int b = grow >> 10, s = grow & 1023;
          if (gcol < 512) {
            int h = gcol >> 6, dh = gcol & 63;
            qo[(((size_t)b * H_ + h) * S_ + s) * DH_ + dh] = f2h(v + bias0[gcol]);
          } else {
            int n2 = gcol - 512;
            int two = n2 >> 9, h = (n2 >> 6) & 7, dh = n2 & 63;
            float vv = v + bias1[n2];
            if (two == 0) ko_[(((size_t)b * H_ + h) * S_ + s) * DH_ + dh] = f2h(vv);
            else          vto[(((size_t)b * H_ + h) * DH_ + dh) * S_ + s] = f2h(vv);
          }
        } else {
          float vp = __shfl_xor(v, 1);
          if ((l15 & 1) == 0) {
            float a = v, b = vp;
            float gv = a / (1.f + __expf(-a)) * b;
            outU[(size_t)grow * (N >> 1) + (gcol >> 1)] = f2bf(gv);
          }
        }
      }
    }
  }
}

// ---------------- 128x64 GEMM for small-N layers (256 blocks, 8 MFMA/iter) ----------------
// EPI 2: +bias0 +auxF(fp32) -> outF ; EPI 4: +auxH(bf16) -> outF
template<int EPI>
__global__ __launch_bounds__(256) void gemm_n64(
    const u16* __restrict__ A, const u16* __restrict__ Bt,
    int M, int N, int K,
    const float* __restrict__ bias0, const float* __restrict__ auxF,
    const u16* __restrict__ auxH, float* __restrict__ outF)
{
  __shared__ u16 As[128 * 32];
  __shared__ u16 Bs[64 * 32];
  int tid = threadIdx.x;
  int gx = blockIdx.x, gy = blockIdx.y;
  int l = tid & 63, w = tid >> 6;
  int l15 = l & 15, quad = l >> 4;
  int wm = (w >> 1) * 64, wn = (w & 1) * 32;
  f32x4 acc[4][2] = {};

  const u16* Ag = A  + (size_t)(gy * 128 + (tid >> 2)) * K + (tid & 3) * 8;
  const u16* Bg = Bt + (size_t)(gx * 64  + (tid >> 2)) * K + (tid & 3) * 8;

  for (int ko = 0; ko < K; ko += 32) {
    __syncthreads();
    gl_lds16(Ag + ko,                  &As[tid * 8]);
    gl_lds16(Ag + (size_t)64 * K + ko, &As[2048 + tid * 8]);
    gl_lds16(Bg + ko,                  &Bs[tid * 8]);
    __syncthreads();
    sh8 af[4], bfr[2];
    #pragma unroll
    for (int mi = 0; mi < 4; mi++)
      af[mi] = *(const sh8*)&As[(wm + mi * 16 + l15) * 32 + quad * 8];
    #pragma unroll
    for (int ni = 0; ni < 2; ni++)
      bfr[ni] = *(const sh8*)&Bs[(wn + ni * 16 + l15) * 32 + quad * 8];
    #pragma unroll
    for (int mi = 0; mi < 4; mi++)
      #pragma unroll
      for (int ni = 0; ni < 2; ni++)
        acc[mi][ni] = __builtin_amdgcn_mfma_f32_16x16x32_bf16(af[mi], bfr[ni], acc[mi][ni], 0, 0, 0);
  }

  #pragma unroll
  for (int mi = 0; mi < 4; mi++) {
    #pragma unroll
    for (int ni = 0; ni < 2; ni++) {
      #pragma unroll
      for (int r = 0; r < 4; r++) {
        int grow = gy * 128 + wm + mi * 16 + quad * 4 + r;
        int gcol = gx * 64 + wn + ni * 16 + l15;
        float v = acc[mi][ni][r];
        if (EPI == 2) v += bias0[gcol] + auxF[(size_t)grow * N + gcol];
        else          v += bf2f(auxH[(size_t)grow * N + gcol]);
        outF[(size_t)grow * N + gcol] = v;
      }
    }
  }
}

// ---------------- sparse attention v6: DMA-pipelined K/V, maskless Taylor softmax2 ----------------
#define RSTRIDE 1032                 // halves; score row stride (2064 B)
#define STAGE_H (16 * RSTRIDE)       // staging region offset, halves
__global__ __launch_bounds__(256, 3) void attn_kernel(
    const u16* __restrict__ q, const u16* __restrict__ kk,
    const u16* __restrict__ vt, u16* __restrict__ attn)
{
  // 33,024 halves scores + 8,192 halves staging (4 waves x 4 KB) = 49,408 B
  __shared__ u16 scb[16 * RSTRIDE + 4 * 2048];

  int tid = threadIdx.x;
  int l = tid & 63, w = tid >> 6;
  int l15 = l & 15, quad = l >> 4;
  int blk = blockIdx.x;
  // XCD-aware swizzle: 4 bh per XCD (1 MB K/V working set per XCD L2)
  int xcd = blk & 7, li = blk >> 3;
  int bh = xcd * 4 + (li & 3);
  int r0 = (li >> 2) << 4;

  const u16* qb = q  + ((size_t)bh * S_ + r0) * DH_;
  const u16* kb = kk + (size_t)bh * S_ * DH_;
  const u16* vb = vt + (size_t)bh * DH_ * S_;

  int ws = STAGE_H + w * 2048;     // per-wave private staging base (halves)
  int lr = l >> 2, lc = l & 3;     // staging row / 16B-chunk for this lane

  h8 aq0 = *(const h8*)(qb + l15 * DH_ + quad * 8);
  h8 aq1 = *(const h8*)(qb + l15 * DH_ + 32 + quad * 8);

  // ---- phase A: e' = exp(score/8 - 8) -> LDS f16, K DMA-staged 2-deep
  // slot layout (2 KB): first KB rows x cols 0..31, second KB rows x cols 32..63
  #pragma unroll
  for (int i = 0; i < 16; i++) {
    if (i == 0) {
      const u16* src = kb + (size_t)((w << 4) + lr) * DH_ + lc * 8;
      gl_lds16(src,      &scb[ws + l * 8]);
      gl_lds16(src + 32, &scb[ws + 512 + l * 8]);
    }
    if (i + 1 < 16) {
      int t0n = (((i + 1) << 2) | w) << 4;
      const u16* src = kb + (size_t)(t0n + lr) * DH_ + lc * 8;
      int sb = ws + ((i + 1) & 1) * 1024;
      gl_lds16(src,      &scb[sb + l * 8]);
      gl_lds16(src + 32, &scb[sb + 512 + l * 8]);
    }
    if (i + 1 < 16) { WAITVM(2); } else { WAITVM(0); }
    int t0 = ((i << 2) | w) << 4;
    int sb = ws + (i & 1) * 1024;
    h8 bk0 = *(const h8*)&scb[sb + l15 * 32 + quad * 8];
    h8 bk1 = *(const h8*)&scb[sb + 512 + l15 * 32 + quad * 8];
    f32x4 s4 = {};
    s4 = __builtin_amdgcn_mfma_f32_16x16x32_f16(bk0, aq0, s4, 0, 0, 0);
    s4 = __builtin_amdgcn_mfma_f32_16x16x32_f16(bk1, aq1, s4, 0, 0, 0);
    h4 hv;
    #pragma unroll
    for (int r = 0; r < 4; r++)
      hv[r] = (_Float16)exp2f(fmaf(s4[r], 0.18033688f, -11.5415603f));  // exp(s/8-8)
    *(h4*)(scb + l15 * RSTRIDE + t0 + quad * 4) = hv;
  }
  __syncthreads();   // B1 (drains K DMAs; staging region reusable)

  // ---- phase B: Z1, then c' = exp(w)/Z2 via packed-f16 Horner
  int row = tid >> 4, l16 = tid & 15;
  u16* rowp = scb + row * RSTRIDE;
  uint32_t kv[32];
  h2f z1a = (h2f)(_Float16)0;
  #pragma unroll
  for (int u = 0; u < 16; u++) {
    uint2 rr = *(const uint2*)(rowp + 4 * l16 + 64 * u);
    kv[2 * u] = rr.x; kv[2 * u + 1] = rr.y;
    z1a = z1a + __builtin_bit_cast(h2f, rr.x);
    z1a = z1a + __builtin_bit_cast(h2f, rr.y);
  }
  float Z1 = (float)z1a[0] + (float)z1a[1];
  #pragma unroll
  for (int d = 1; d < 16; d <<= 1) Z1 += __shfl_xor(Z1, d);
  _Float16 izh = (_Float16)(1.0f / Z1);
  h2f izv; izv[0] = izh; izv[1] = izh;
  h2f onev; onev[0] = (_Float16)1.f; onev[1] = (_Float16)1.f;
  h2f c2v;  c2v[0] = (_Float16)0.5f; c2v[1] = (_Float16)0.5f;
  h2f c6v;  c6v[0] = (_Float16)(1.f/6.f); c6v[1] = (_Float16)(1.f/6.f);

  h2f sacc = (h2f)(_Float16)0;
  h2f cm1s[32];
  #pragma unroll
  for (int t = 0; t < 32; t++) {
    h2f e = __builtin_bit_cast(h2f, kv[t]);
    h2f wv = e * izv;
    h2f p = wv * c6v + c2v;
    h2f qq = wv * p + onev;
    h2f cm1 = wv * qq;
    sacc = sacc + cm1;
    cm1s[t] = cm1;
  }
  float s2 = (float)sacc[0] + (float)sacc[1];
  #pragma unroll
  for (int d = 1; d < 16; d <<= 1) s2 += __shfl_xor(s2, d);
  float Z2 = 1024.0f + s2;
  _Float16 zh = (_Float16)(1.0f / Z2);
  h2f zv; zv[0] = zh; zv[1] = zh;

  #pragma unroll
  for (int u = 0; u < 16; u++) {
    h2f a = cm1s[2 * u] * zv + zv;
    h2f b = cm1s[2 * u + 1] * zv + zv;
    uint2 ov;
    ov.x = __builtin_bit_cast(uint32_t, a);
    ov.y = __builtin_bit_cast(uint32_t, b);
    *(uint2*)(rowp + 4 * l16 + 64 * u) = ov;
  }
  __syncthreads();   // B2

  // ---- phase E: o = c' @ V, V DMA-staged 4-deep (1 KB slots, per-wave private)
  int n0 = w << 4;
  const u16* crow = scb + l15 * RSTRIDE;
  const u16* vsrc = vb + (size_t)(n0 + lr) * S_ + lc * 8;
  f32x4 oacc = {};
  gl_lds16(vsrc,      &scb[ws + l * 8]);
  gl_lds16(vsrc + 32, &scb[ws + 512 + l * 8]);
  gl_lds16(vsrc + 64, &scb[ws + 1024 + l * 8]);
  #pragma unroll
  for (int kt = 0; kt < 32; kt++) {
    if (kt + 3 < 32)
      gl_lds16(vsrc + (kt + 3) * 32, &scb[ws + ((kt + 3) & 3) * 512 + l * 8]);
    if (kt < 29) { WAITVM(3); } else if (kt == 29) { WAITVM(2); }
    else if (kt == 30) { WAITVM(1); } else { WAITVM(0); }
    h8 ca = *(const h8*)(crow + kt * 32 + quad * 8);
    h8 vv = *(const h8*)&scb[ws + (kt & 3) * 512 + l15 * 32 + quad * 8];
    oacc = __builtin_amdgcn_mfma_f32_16x16x32_f16(ca, vv, oacc, 0, 0, 0);
  }
  int b = bh >> 3, hh = bh & 7;
  #pragma unroll
  for (int r = 0; r < 4; r++) {
    int rr = quad * 4 + r;
    attn[((size_t)b * S_ + r0 + rr) * D_ + hh * DH_ + n0 + l15] = f2bf(oacc[r]);
  }
}

// ---------------- RMS norm over D per row: fp32 in, bf16 out ----------------
__global__ __launch_bounds__(128) void rms_kernel(const float* __restrict__ in,
                                                  const float* __restrict__ w,
                                                  u16* __restrict__ out) {
  int row = blockIdx.x;
  int tid = threadIdx.x;
  const float* r = in + (size_t)row * D_;
  float v0 = r[tid], v1 = r[tid + 128], v2 = r[tid + 256], v3 = r[tid + 384];
  float s = v0 * v0 + v1 * v1 + v2 * v2 + v3 * v3;
  #pragma unroll
  for (int d = 1; d < 64; d <<= 1) s += __shfl_xor(s, d);
  __shared__ float red[2];
  if ((tid & 63) == 0) red[tid >> 6] = s;
  __syncthreads();
  s = red[0] + red[1];
  float rs = rsqrtf(s * (1.0f / 512.0f) + 1e-6f);
  out[(size_t)row * D_ + tid      ] = f2bf(v0 * rs * w[tid      ]);
  out[(size_t)row * D_ + tid + 128] = f2bf(v1 * rs * w[tid + 128]);
  out[(size_t)row * D_ + tid + 256] = f2bf(v2 * rs * w[tid + 256]);
  out[(size_t)row * D_ + tid + 384] = f2bf(v3 * rs * w[tid + 384]);
}

// ---------------- instance norm: two-stage stats ----------------
__global__ __launch_bounds__(256) void inorm_stats1(const float* __restrict__ y,
                                                    float* __restrict__ part) {
  int b = blockIdx.x, dc = blockIdx.y, sc = blockIdx.z;
  int dl = threadIdx.x & 63, sl = threadIdx.x >> 6;
  int d = dc * 64 + dl;
  const float* yb = y + (size_t)b * S_ * D_ + (size_t)(sc * 64 + sl * 16) * D_ + d;
  float s1 = 0.f, s2 = 0.f;
  #pragma unroll
  for (int i = 0; i < 16; i++) {
    float v = yb[(size_t)i * D_];
    s1 += v; s2 += v * v;
  }
  __shared__ float r1[256], r2[256];
  r1[threadIdx.x] = s1; r2[threadIdx.x] = s2;
  __syncthreads();
  if (sl == 0) {
    s1 = r1[dl] + r1[dl + 64] + r1[dl + 128] + r1[dl + 192];
    s2 = r2[dl] + r2[dl + 64] + r2[dl + 128] + r2[dl + 192];
    float2 p; p.x = s1; p.y = s2;
    *(float2*)&part[(((size_t)(b * 8 + dc) * 64 + dl) * 16 + sc) * 2] = p;
  }
}

__global__ __launch_bounds__(256) void inorm_stats2(const float* __restrict__ part,
                                                    float* __restrict__ stats) {
  int idx = blockIdx.x * 256 + threadIdx.x;   // (b*512+d), 2048 total
  float s1 = 0.f, s2 = 0.f;
  #pragma unroll
  for (int i = 0; i < 16; i++) {
    float2 p = *(const float2*)&part[((size_t)idx * 16 + i) * 2];
    s1 += p.x; s2 += p.y;
  }
  float m = s1 * (1.f / 1024.f);
  float var = s2 * (1.f / 1024.f) - m * m;
  stats[idx * 2]     = m;
  stats[idx * 2 + 1] = rsqrtf(var + 1e-5f);
}

__global__ __launch_bounds__(256) void inorm_apply(const float* __restrict__ y,
                                                   const float* __restrict__ stats,
                                                   const float* __restrict__ w,
                                                   const float* __restrict__ bias,
                                                   float* __restrict__ out) {
  int row = blockIdx.x;
  int b = row >> 10;
  int tid = threadIdx.x;
  #pragma unroll
  for (int i = 0; i < 2; i++) {
    int d = tid + i * 256;
    float m  = stats[((size_t)b * D_ + d) * 2];
    float rs = stats[((size_t)b * D_ + d) * 2 + 1];
    float v = y[(size_t)row * D_ + d];
    out[(size_t)row * D_ + d] = (v - m) * rs * w[d] + bias[d];
  }
}

// ---------------- launch ----------------
extern "C" void kernel_launch(void* const* d_in, const int* in_sizes, int n_in,
                              void* d_out, int out_size, void* d_ws, size_t ws_size,
                              hipStream_t stream) {
  const float* x    = (const float*)d_in[0];
  const float* Wq   = (const float*)d_in[1];
  const float* bq   = (const float*)d_in[2];
  const float* Wkv  = (const float*)d_in[3];
  const float* bkv  = (const float*)d_in[4];
  const float* Wo   = (const float*)d_in[5];
  const float* bo   = (const float*)d_in[6];
  const float* rmsw = (const float*)d_in[7];
  const float* l1   = (const float*)d_in[8];
  const float* l2   = (const float*)d_in[9];
  const float* l3   = (const float*)d_in[10];
  const float* inw  = (const float*)d_in[11];
  const float* inb  = (const float*)d_in[12];
  float* out = (float*)d_out;

  char* ws = (char*)d_ws;
  size_t off = 0;
  auto alloc = [&](size_t n) { char* p = ws + off; off += (n + 255) & ~(size_t)255; return p; };
  u16*  xb   = (u16*) alloc((size_t)M_ * D_ * 2);
  u16*  Wt1  = (u16*) alloc((size_t)1536 * 512 * 2);
  u16*  Wot  = (u16*) alloc((size_t)512 * 512 * 2);
  u16*  W12t = (u16*) alloc((size_t)3072 * 512 * 2);   // interleaved l1/l2
  u16*  l3t  = (u16*) alloc((size_t)512 * 1536 * 2);
  u16*  qb   = (u16*) alloc((size_t)M_ * D_ * 2);      // f16 [B,H,S,DH]
  u16*  kb   = (u16*) alloc((size_t)M_ * D_ * 2);      // f16 [B,H,S,DH]
  u16*  vtb  = (u16*) alloc((size_t)M_ * D_ * 2);      // f16 [B,H,DH,S]
  u16*  attn = (u16*) alloc((size_t)M_ * D_ * 2);      // bf16 [B,S,D]
  float* tmpF = (float*)alloc((size_t)M_ * D_ * 4);
  u16*  hhat = (u16*) alloc((size_t)M_ * D_ * 2);
  u16*  g    = (u16*) alloc((size_t)M_ * INNER_ * 2);
  float* part  = (float*)alloc((size_t)B_ * D_ * 16 * 2 * 4);
  float* stats = (float*)alloc((size_t)B_ * D_ * 2 * 4);

  transpose_all<<<832, 256, 0, stream>>>(Wq, Wkv, Wo, l1, l2, l3, Wt1, Wot, W12t, l3t);
  f2b_kernel<<<2048, 256, 0, stream>>>(x, xb);

  gemm_bt<1><<<dim3(12, 32), 256, 0, stream>>>(xb, Wt1, M_, 1536, 512,
      bq, bkv, nullptr, qb, kb, vtb);

  attn_kernel<<<2048, 256, 0, stream>>>(qb, kb, vtb, attn);

  gemm_n64<2><<<dim3(8, 32), 256, 0, stream>>>(attn, Wot, M_, 512, 512,
      bo, x, nullptr, tmpF);

  rms_kernel<<<4096, 128, 0, stream>>>(tmpF, rmsw, hhat);

  // FFN up + silu fused: writes g [M, 1536] directly
  gemm_bt<3><<<dim3(24, 32), 256, 0, stream>>>(hhat, W12t, M_, 3072, 512,
      nullptr, nullptr, g, nullptr, nullptr, nullptr);

  gemm_n64<4><<<dim3(8, 32), 256, 0, stream>>>(g, l3t, M_, 512, 1536,
      nullptr, nullptr, hhat, tmpF);

  inorm_stats1<<<dim3(4, 8, 16), 256, 0, stream>>>(tmpF, part);
  inorm_stats2<<<8, 256, 0, stream>>>(part, stats);
  inorm_apply<<<4096, 256, 0, stream>>>(tmpF, stats, inw, inb, out);
}